// Round 12
// baseline (364.603 us; speedup 1.0000x reference)
//
#include <hip/hip_runtime.h>
#include <hip/hip_bf16.h>

#define M_ 2
#define D_ 128
#define NI_ 131072
#define L_ 4
#define NPL_ 2048
#define R_ 8
#define T_ 32
#define N_ (NI_ + L_ * NPL_)   // 139264
#define ND_ (L_ * NPL_)        // 8192 deriv nodes
#define PART4_ 1184            // 512 init + 640 fast + 1 deriv-posneg + pad (per model)

typedef __bf16 bf16x8 __attribute__((ext_vector_type(8)));
typedef float f32x4 __attribute__((ext_vector_type(4)));

// ---- ws layout (bytes) ----
#define OFF_W1T    0u            // [M][R][128(d)][256(c)] bf16 = 1048576
#define OFF_W2T    1048576u      // [M][R][128(e)][128(d)] bf16 = 524288
#define OFF_WE1T   1572864u      // [M][128(e)][128(d)] bf16    = 65536
#define OFF_TAB    1638400u      // [M][T][128] bf16            = 16384
#define OFF_SVEC   1654784u      // [M][128] bf16               = 512
#define OFF_SORTED 1655296u      // [L][2048] int               = 32768
#define OFF_STARTS 1688064u      // [L][8] int                  = 128
#define OFF_CNTF   1688192u      // [L][8] int                  = 128
#define OFF_CNTA   1688320u      // [L][8] int                  = 128
#define OFF_EA2    1688448u      // [M][64][32][2] f32          = 32768
#define OFF_EWB    1721216u      // [M][128][2] f32             = 2048
#define OFF_PA     1723264u      // [M][1184] f32 = 9472   (pA..pTn contiguous, 47360 B)
#define OFF_PB     1732736u
#define OFF_PPOK   1742208u
#define OFF_PNOK   1751680u
#define OFF_PTP    1761152u      // [1184] f32
#define OFF_PTN    1765888u      // [1184] f32 ; end 1770624
#define OFF_G      1770624u      // [M][R][2][33][128] f32 = 540672
#define OFF_STORE  2311296u      // [M][8192][128] bf16 = 4194304
#define OFF_FSG    6505600u      // [8] int
#define OFF_CFG    6505632u      // [8] int
#define OFF_FLIST  6505664u      // [8192] int ; end ~6.54MB

__device__ __forceinline__ unsigned short f2bu(float f) {
  unsigned int u = __float_as_uint(f);
  u += 0x7fffu + ((u >> 16) & 1u);        // RNE (finite values only)
  return (unsigned short)(u >> 16);
}
__device__ __forceinline__ bf16x8 ldb8(const unsigned short* p) {
  return *reinterpret_cast<const bf16x8*>(p);
}

// value of node `row` (global id), 8 dims from d0 (slow path only).
__device__ __forceinline__ bf16x8 node_chunk(int m, int row, int d0,
    const unsigned short* tab, const unsigned short* svec,
    const unsigned short* sd, const int* thax, const float* sine) {
  if (row < NI_) {
    bf16x8 tv = ldb8(&tab[(m * T_ + thax[row]) * D_ + d0]);
    bf16x8 sv = ldb8(&svec[m * D_ + d0]);
    float sn = sine[row];
    bf16x8 r;
#pragma unroll
    for (int j = 0; j < 8; ++j)
      r[j] = (__bf16)((float)tv[j] + sn * (float)sv[j]);
    return r;
  }
  return ldb8(&sd[(size_t)(m * ND_ + (row - NI_)) * D_ + d0]);
}

// ================= mega-prep =================
// jobs: [0,800) transposes; 800 tab/svec; [801,1329) gprep; [1329,1363) eaprep;
//       [1363,1367) per-layer rsort; 1367 fast-list sort; 1368 zero partials.
__global__ __launch_bounds__(256) void megaprep_kernel(
    const float* W1, const float* W2, const float* We1,
    const float* init_table, const float* s_vec,
    const float* b1, const float* be1, const float* we2,
    const int* ridx, const int* par,
    unsigned short* W1T, unsigned short* W2T, unsigned short* We1T,
    unsigned short* tab, unsigned short* svec,
    float* G, float* EA2, float* EWB,
    int* sorted, int* starts, int* cntF, int* cntA,
    int* fsg, int* cfg, int* fastlist, unsigned int* pzero) {
  __shared__ float smem[1056];
  __shared__ int icnt[16], ioff[16];
  int job = blockIdx.x;
  int tid = threadIdx.x;

  if (job < 800) {                       // -------- transposes --------
    int z, rblk, cblk;
    if (job < 512)      { z = job >> 5;            rblk = (job & 31) >> 2; cblk = job & 3; }
    else if (job < 768) { int q = job - 512; z = 16 + (q >> 4); rblk = (q & 15) >> 2; cblk = q & 3; }
    else                { int q = job - 768; z = 32 + (q >> 4); rblk = (q & 15) >> 2; cblk = q & 3; }
    const float* src; unsigned short* dst; int R;
    if (z < 16)      { src = W1  + (size_t)z * 32768;        dst = W1T  + (size_t)z * 32768;        R = 256; }
    else if (z < 32) { src = W2  + (size_t)(z - 16) * 16384; dst = W2T  + (size_t)(z - 16) * 16384; R = 128; }
    else             { src = We1 + (size_t)(z - 32) * 16384; dst = We1T + (size_t)(z - 32) * 16384; R = 128; }
    int r0 = rblk * 32, c0 = cblk * 32;
    float (*tile)[33] = (float(*)[33])smem;
    int tx = tid & 31, ty = tid >> 5;
#pragma unroll
    for (int k = 0; k < 4; ++k)
      tile[ty + 8 * k][tx] = src[(size_t)(r0 + ty + 8 * k) * D_ + c0 + tx];
    __syncthreads();
#pragma unroll
    for (int k = 0; k < 4; ++k)
      dst[(size_t)(c0 + ty + 8 * k) * R + r0 + tx] = f2bu(tile[tx][ty + 8 * k]);
  } else if (job == 800) {               // -------- tab/svec convert --------
    for (int i = tid; i < 8448; i += 256) {
      if (i < 8192) tab[i] = f2bu(init_table[i]);
      else svec[i - 8192] = f2bu(s_vec[i - 8192]);
    }
  } else if (job < 1329) {               // -------- gprep: G[m][r][slot][t][e] --------
    int q = job - 801;
    int t = q / 16, mr = q & 15;         // t in [0,32], 32 == svec row
    int m = mr >> 3;
    int slot = tid >> 7, e = tid & 127;
    const float* vec = (t < 32) ? &init_table[(size_t)(m * T_ + t) * D_]
                                : &s_vec[(size_t)m * D_];
    if (tid < 128) smem[tid] = vec[tid];
    __syncthreads();
    const float* w = &W1[((size_t)mr * 256 + slot * 128) * D_];
    float acc = 0.f;
#pragma unroll 8
    for (int c = 0; c < 128; ++c) acc = fmaf(smem[c], w[c * D_ + e], acc);
    if (slot == 0 && t < 32) acc += b1[mr * D_ + e];   // fold b1 into slot-a rows
    G[((size_t)(mr * 2 + slot) * 33 + t) * D_ + e] = acc;
  } else if (job < 1363) {               // -------- eaprep: eval-init tables --------
    int q = job - 1329;
    int m = q / 17, t = (q % 17) * 2 + (tid >> 7);
    int e = tid & 127;
    if (t <= 32) {
      const float* vec = (t < 32) ? &init_table[(size_t)(m * T_ + t) * D_]
                                  : &s_vec[(size_t)m * D_];
      const float* w = &We1[(size_t)m * D_ * D_];
      float acc = 0.f;
#pragma unroll 8
      for (int d = 0; d < 128; ++d) acc = fmaf(vec[d], w[d * D_ + e], acc);
      if (t < 32) {
        EA2[m * 4096 + ((e >> 1) * 32 + t) * 2 + (e & 1)] = acc + be1[m * D_ + e];
      } else {
        EWB[(m * D_ + e) * 2 + 0] = acc;
        EWB[(m * D_ + e) * 2 + 1] = we2[m * D_ + e];
      }
    }
  } else if (job < 1367) {               // -------- per-layer 16-bucket rsort --------
    int l = job - 1363;
    if (tid < 16) icnt[tid] = 0;
    __syncthreads();
    for (int n = tid; n < NPL_; n += 256) {
      int r = ridx[l * NPL_ + n];
      int p0 = par[(l * NPL_ + n) * 2 + 0], p1 = par[(l * NPL_ + n) * 2 + 1];
      int slow = (p0 >= NI_ || p1 >= NI_) ? 1 : 0;
      atomicAdd(&icnt[r * 2 + slow], 1);
    }
    __syncthreads();
    if (tid == 0) {
      int run = 0;
      for (int b = 0; b < 16; ++b) { ioff[b] = run; run += icnt[b]; }
      for (int r = 0; r < R_; ++r) {
        starts[l * R_ + r] = ioff[2 * r];
        cntF[l * R_ + r] = icnt[2 * r];
        cntA[l * R_ + r] = icnt[2 * r] + icnt[2 * r + 1];
      }
    }
    __syncthreads();
    for (int n = tid; n < NPL_; n += 256) {
      int r = ridx[l * NPL_ + n];
      int p0 = par[(l * NPL_ + n) * 2 + 0], p1 = par[(l * NPL_ + n) * 2 + 1];
      int slow = (p0 >= NI_ || p1 >= NI_) ? 1 : 0;
      int p = atomicAdd(&ioff[r * 2 + slow], 1);
      sorted[l * NPL_ + p] = n;   // order within bucket irrelevant: row-independent math
    }
  } else if (job == 1367) {              // -------- global fast-list sort by rule --------
    if (tid < 8) icnt[tid] = 0;
    __syncthreads();
    for (int g = tid; g < ND_; g += 256) {
      int p0 = par[2 * g], p1 = par[2 * g + 1];
      if (p0 < NI_ && p1 < NI_) atomicAdd(&icnt[ridx[g]], 1);
    }
    __syncthreads();
    if (tid == 0) {
      int run = 0;
      for (int r = 0; r < R_; ++r) {
        ioff[r] = run; fsg[r] = run; cfg[r] = icnt[r]; run += icnt[r];
      }
    }
    __syncthreads();
    for (int g = tid; g < ND_; g += 256) {
      int p0 = par[2 * g], p1 = par[2 * g + 1];
      if (p0 < NI_ && p1 < NI_) {
        int p = atomicAdd(&ioff[ridx[g]], 1);
        fastlist[p] = g;     // g = l*NPL+n = deriv index
      }
    }
  } else {                               // -------- zero partial arrays (47360 B) --------
    for (int i = tid; i < 11840; i += 256) pzero[i] = 0u;
  }
}

// ================= main: fast rows (+fused eval) + eval-init + deriv pos/neg sums ====
// grid 2306. bid<1280: fast tile. bid<2304: eval-init. bid>=2304: deriv pos/neg sum.
__global__ __launch_bounds__(256) void main_kernel(
    const int* thax, const float* sine, const int* par,
    const float* pos, const float* neg,
    const float* b2, const float* tweaks,
    const float* G, const unsigned short* W2T, const unsigned short* We1T,
    const float* EA2, const float* EWB,
    const float* be1, const float* we2, const float* be2,
    const int* fsg, const int* cfg, const int* fastlist,
    unsigned short* sd,
    float* pA, float* pB, float* pPok, float* pNok, float* pTp, float* pTn) {
  __shared__ float sbuf[4448];
  int bid = blockIdx.x;
  int tid = threadIdx.x;
  int w = tid >> 6, lane = tid & 63;

  if (bid < 1280) {                       // ---------- fast rows ----------
    int m = bid / 640, q = bid % 640;
    int r = q / 80, tile = q % 80;
    int cnt = cfg[r];
    int base = tile * 16;
    if (base >= cnt) return;
    unsigned short* h_lds = (unsigned short*)sbuf;       // [16][128] bf16
    int*   t0a  = (int*)(sbuf + 1024);
    int*   t1a  = t0a + 16;
    float* s0a  = (float*)(t1a + 16);
    float* s1a  = s0a + 16;
    int*   gida = (int*)(s1a + 16);
    float* red2 = sbuf + 1104;                           // [4][16]
    if (tid < 16) {
      int loc = base + tid; if (loc >= cnt) loc = cnt - 1;
      int gid = fastlist[fsg[r] + loc];
      int p0 = par[2 * gid], p1 = par[2 * gid + 1];
      t0a[tid] = thax[p0]; s0a[tid] = sine[p0];
      t1a[tid] = thax[p1]; s1a[tid] = sine[p1];
      gida[tid] = gid;
    }
    __syncthreads();
    const float* Gm = &G[(size_t)(m * R_ + r) * 8448];
    {                                     // coop-build h (1 thread = row x 8 dims)
      int row = tid >> 4, seg = tid & 15, d0 = seg * 8;
      int t0 = t0a[row], t1 = t1a[row];
      float s0 = s0a[row], s1 = s1a[row];
      const float* pa = &Gm[t0 * 128 + d0];
      const float* pb = &Gm[(33 + t1) * 128 + d0];
      const float* pu = &Gm[4096 + d0];
      const float* pv = &Gm[8320 + d0];
      bf16x8 hv;
#pragma unroll
      for (int half = 0; half < 2; ++half) {
        float4 a = *(const float4*)(pa + half * 4);
        float4 b = *(const float4*)(pb + half * 4);
        float4 u = *(const float4*)(pu + half * 4);
        float4 v = *(const float4*)(pv + half * 4);
        hv[half * 4 + 0] = (__bf16)fmaxf(a.x + b.x + s0 * u.x + s1 * v.x, 0.f);
        hv[half * 4 + 1] = (__bf16)fmaxf(a.y + b.y + s0 * u.y + s1 * v.y, 0.f);
        hv[half * 4 + 2] = (__bf16)fmaxf(a.z + b.z + s0 * u.z + s1 * v.z, 0.f);
        hv[half * 4 + 3] = (__bf16)fmaxf(a.w + b.w + s0 * u.w + s1 * v.w, 0.f);
      }
      *(bf16x8*)&h_lds[row * 128 + (d0 ^ ((row & 7) << 3))] = hv;
    }
    __syncthreads();
    int l15 = lane & 15, l4 = lane >> 4;  // GEMM2: 4 waves x 2 f each
    const unsigned short* w2b = &W2T[(size_t)(m * R_ + r) * D_ * D_];
    f32x4 acc[2];
    acc[0] = (f32x4){0.f, 0.f, 0.f, 0.f};
    acc[1] = (f32x4){0.f, 0.f, 0.f, 0.f};
#pragma unroll
    for (int kc = 0; kc < 4; ++kc) {
      int d0 = kc * 32 + l4 * 8;
      bf16x8 a2 = ldb8(&h_lds[l15 * 128 + (d0 ^ ((l15 & 7) << 3))]);
#pragma unroll
      for (int f = 0; f < 2; ++f) {
        int fg = w * 2 + f;
        bf16x8 b = ldb8(&w2b[(fg * 16 + l15) * D_ + d0]);
        acc[f] = __builtin_amdgcn_mfma_f32_16x16x32_bf16(a2, b, acc[f], 0, 0, 0);
      }
    }
    float tw1 = tweaks[m * 2 + 1];
    const float* b2v = &b2[(m * R_ + r) * D_];
    __syncthreads();                      // done reading h_lds (GEMM2)
#pragma unroll
    for (int i = 0; i < 4; ++i) {
      int row = l4 * 4 + i;
      int g = base + row;
#pragma unroll
      for (int f = 0; f < 2; ++f) {
        int e = (w * 2 + f) * 16 + l15;
        unsigned short val = f2bu(acc[f][i] + b2v[e] + tw1);
        h_lds[row * 128 + (e ^ ((row & 7) << 3))] = val;
        if (g < cnt) sd[(size_t)(m * ND_ + gida[row]) * D_ + e] = val;
      }
    }
    __syncthreads();
    // fused eval: out @ We1 -> relu -> we2
    f32x4 ae[2];
    ae[0] = (f32x4){0.f, 0.f, 0.f, 0.f};
    ae[1] = (f32x4){0.f, 0.f, 0.f, 0.f};
    const unsigned short* we1b = &We1T[(size_t)m * D_ * D_];
#pragma unroll
    for (int kc = 0; kc < 4; ++kc) {
      int d0 = kc * 32 + l4 * 8;
      bf16x8 a2 = ldb8(&h_lds[l15 * 128 + (d0 ^ ((l15 & 7) << 3))]);
#pragma unroll
      for (int f = 0; f < 2; ++f) {
        int fg = w * 2 + f;
        bf16x8 b = ldb8(&we1b[(fg * 16 + l15) * D_ + d0]);
        ae[f] = __builtin_amdgcn_mfma_f32_16x16x32_bf16(a2, b, ae[f], 0, 0, 0);
      }
    }
    float part[4] = {0.f, 0.f, 0.f, 0.f};
#pragma unroll
    for (int f = 0; f < 2; ++f) {
      int e = (w * 2 + f) * 16 + l15;
      float bb = be1[m * D_ + e];
      float wv = we2[m * D_ + e];
#pragma unroll
      for (int i = 0; i < 4; ++i) {
        float he = ae[f][i] + bb;
        he = he > 0.f ? he : 0.f;
        part[i] += he * wv;
      }
    }
#pragma unroll
    for (int mask = 1; mask < 16; mask <<= 1) {
#pragma unroll
      for (int i = 0; i < 4; ++i) part[i] += __shfl_xor(part[i], mask, 64);
    }
    if (l15 == 0) {
#pragma unroll
      for (int i = 0; i < 4; ++i) red2[w * 16 + l4 * 4 + i] = part[i];
    }
    __syncthreads();
    if (tid < 16) {
      int g = base + tid;
      float v6[4] = {0.f, 0.f, 0.f, 0.f};
      if (g < cnt) {
        float logit = red2[tid] + red2[16 + tid] + red2[32 + tid] + red2[48 + tid]
                    + be2[m] + tweaks[m * 2 + 0];
        int grow = NI_ + gida[tid];
        float p_ = pos[grow], n_ = neg[grow];
        float lse = log1pf(__expf(-fabsf(logit)));
        v6[0] = p_ * (fmaxf(-logit, 0.f) + lse);
        v6[1] = n_ * (fmaxf(logit, 0.f) + lse);
        v6[2] = logit >= 0.f ? p_ : 0.f;
        v6[3] = logit < 0.f ? n_ : 0.f;
      }
#pragma unroll
      for (int mask = 1; mask < 16; mask <<= 1) {
#pragma unroll
        for (int qq = 0; qq < 4; ++qq) v6[qq] += __shfl_xor(v6[qq], mask, 64);
      }
      if (tid == 0) {
        int slot = 512 + r * 80 + tile;
        pA[m * PART4_ + slot] = v6[0];
        pB[m * PART4_ + slot] = v6[1];
        pPok[m * PART4_ + slot] = v6[2];
        pNok[m * PART4_ + slot] = v6[3];
      }
    }
  } else if (bid < 2304) {                // ---------- eval-init ----------
    int q = bid - 1280;
    int m = q >> 9, xb = q & 511;
    float* lea = sbuf;                    // [p=64][t=32][2]
    float* lwb = sbuf + 4096;             // [e=128][{EB,we2}]
    float* red = sbuf + 4352;             // [q*16 + slot]
    for (int i = tid; i < 4096; i += 256) lea[i] = EA2[m * 4096 + i];
    if (tid < 256) lwb[tid] = EWB[m * 256 + tid];
    __syncthreads();
    int row = xb * 256 + tid;
    int t = thax[row];
    float s = sine[row];
    float acc = 0.f;
#pragma unroll 8
    for (int p = 0; p < 64; ++p) {
      float2 ea = *(const float2*)&lea[(p * 32 + t) * 2];
      float4 wb = *(const float4*)&lwb[p * 4];
      float x0 = fmaf(s, wb.x, ea.x); x0 = fmaxf(x0, 0.f);
      acc = fmaf(x0, wb.y, acc);
      float x1 = fmaf(s, wb.z, ea.y); x1 = fmaxf(x1, 0.f);
      acc = fmaf(x1, wb.w, acc);
    }
    float logit = acc + be2[m] + tweaks[m * 2 + 0];
    float p_ = pos[row], n_ = neg[row];
    float lse = log1pf(__expf(-fabsf(logit)));
    float v[6];
    v[0] = p_ * (fmaxf(-logit, 0.f) + lse);
    v[1] = n_ * (fmaxf(logit, 0.f) + lse);
    v[2] = logit >= 0.f ? p_ : 0.f;
    v[3] = logit < 0.f ? n_ : 0.f;
    v[4] = p_; v[5] = n_;
#pragma unroll
    for (int mask = 1; mask < 64; mask <<= 1) {
#pragma unroll
      for (int k = 0; k < 6; ++k) v[k] += __shfl_xor(v[k], mask, 64);
    }
    if (lane == 0) {
#pragma unroll
      for (int k = 0; k < 6; ++k) red[k * 16 + w] = v[k];
    }
    __syncthreads();
    if (tid == 0) {
      float t6[6];
#pragma unroll
      for (int k = 0; k < 6; ++k)
        t6[k] = red[k * 16 + 0] + red[k * 16 + 1] + red[k * 16 + 2] + red[k * 16 + 3];
      pA[m * PART4_ + xb] = t6[0];
      pB[m * PART4_ + xb] = t6[1];
      pPok[m * PART4_ + xb] = t6[2];
      pNok[m * PART4_ + xb] = t6[3];
      if (m == 0) { pTp[xb] = t6[4]; pTn[xb] = t6[5]; }
    }
  } else {                                // ---------- deriv pos/neg total ----------
    int j = bid - 2304;                   // 0: pos, 1: neg
    float* red = sbuf;
    const float* src = j ? neg : pos;
    float s = 0.f;
    for (int i = NI_ + tid; i < N_; i += 256) s += src[i];
#pragma unroll
    for (int mask = 1; mask < 64; mask <<= 1) s += __shfl_xor(s, mask, 64);
    if (lane == 0) red[w] = s;
    __syncthreads();
    if (tid == 0) {
      float t = red[0] + red[1] + red[2] + red[3];
      if (j == 0) pTp[1152] = t; else pTn[1152] = t;
    }
  }
}

// ================= tail: slow layers 1..3 + per-model finalize =================
// grid 2 (one block per model), 512 threads = 8 single-wave tile units.
// All cross-tile deps are intra-block (same CU): __syncthreads between layers.
__global__ __launch_bounds__(512) void tail_kernel(
    const int* thax, const float* sine, const int* par,
    const float* b1, const float* b2, const float* tweaks,
    const float* pos, const float* neg,
    const float* be1, const float* we2, const float* be2,
    const unsigned short* tab, const unsigned short* svec,
    const unsigned short* W1T, const unsigned short* W2T,
    const unsigned short* We1T,
    const int* sorted, const int* starts, const int* cntF, const int* cntA,
    unsigned short* sd,
    const float* pA, const float* pB, const float* pPok, const float* pNok,
    const float* pTp, const float* pTn, float* out) {
  __shared__ unsigned short h_all[8][2048];   // 8 units x 16x128 bf16 = 32KB
  __shared__ float wred[8][6];
  __shared__ float fin[8][6];
  int m = blockIdx.x;
  int tid = threadIdx.x;
  int unit = tid >> 6, lane = tid & 63;
  int l15 = lane & 15, l4 = lane >> 4;
  unsigned short* h_lds = h_all[unit];
  float v6[6] = {0.f, 0.f, 0.f, 0.f, 0.f, 0.f};
  float tw1 = tweaks[m * 2 + 1];
  float tw0 = tweaks[m * 2 + 0];
  float bev = be2[m];
  const unsigned short* we1b = &We1T[(size_t)m * D_ * D_];

  for (int l = 1; l < L_; ++l) {
    int wcount = 0;
    for (int r = 0; r < R_; ++r) {
      int cF = cntF[l * R_ + r];
      int cS = cntA[l * R_ + r] - cF;
      int start = starts[l * R_ + r] + cF;
      int nt = (cS + 15) >> 4;
      const unsigned short* w1b = &W1T[(size_t)(m * R_ + r) * D_ * 256];
      const unsigned short* w2b = &W2T[(size_t)(m * R_ + r) * D_ * D_];
      const float* b1v = &b1[(m * R_ + r) * D_];
      const float* b2v = &b2[(m * R_ + r) * D_];
      for (int t = 0; t < nt; ++t, ++wcount) {
        if ((wcount & 7) != unit) continue;
        int base = t * 16;
        int loc = base + l15; if (loc >= cS) loc = cS - 1;
        int node = sorted[l * NPL_ + start + loc];
        int p0 = par[(l * NPL_ + node) * 2 + 0];
        int p1 = par[(l * NPL_ + node) * 2 + 1];
        bf16x8 av[8];
#pragma unroll
        for (int kc = 0; kc < 8; ++kc) {
          int k = kc * 32 + l4 * 8;
          int p = (k < 128) ? p0 : p1;
          av[kc] = node_chunk(m, p, k & 127, tab, svec, sd, thax, sine);
        }
        f32x4 acch[8];
#pragma unroll
        for (int f = 0; f < 8; ++f) acch[f] = (f32x4){0.f, 0.f, 0.f, 0.f};
#pragma unroll
        for (int kc = 0; kc < 8; ++kc) {
          int k = kc * 32 + l4 * 8;
#pragma unroll
          for (int f = 0; f < 8; ++f) {
            bf16x8 b = ldb8(&w1b[(f * 16 + l15) * 256 + k]);
            acch[f] = __builtin_amdgcn_mfma_f32_16x16x32_bf16(av[kc], b, acch[f], 0, 0, 0);
          }
        }
#pragma unroll
        for (int f = 0; f < 8; ++f) {
          int d = f * 16 + l15;
          float bb = b1v[d];
#pragma unroll
          for (int i = 0; i < 4; ++i) {
            int row = l4 * 4 + i;
            float h = acch[f][i] + bb;
            h = h > 0.f ? h : 0.f;
            h_lds[row * 128 + (d ^ ((row & 7) << 3))] = f2bu(h);
          }
        }
        // single-wave LDS write->read: DS ops are wave-FIFO; fence compiler reordering
        asm volatile("s_waitcnt lgkmcnt(0)" ::: "memory");
        __builtin_amdgcn_sched_barrier(0);
        f32x4 acco[8];
#pragma unroll
        for (int f = 0; f < 8; ++f) acco[f] = (f32x4){0.f, 0.f, 0.f, 0.f};
#pragma unroll
        for (int kc = 0; kc < 4; ++kc) {
          int d0 = kc * 32 + l4 * 8;
          bf16x8 a2 = ldb8(&h_lds[l15 * 128 + (d0 ^ ((l15 & 7) << 3))]);
#pragma unroll
          for (int f = 0; f < 8; ++f) {
            bf16x8 b = ldb8(&w2b[(f * 16 + l15) * D_ + d0]);
            acco[f] = __builtin_amdgcn_mfma_f32_16x16x32_bf16(a2, b, acco[f], 0, 0, 0);
          }
        }
        asm volatile("s_waitcnt lgkmcnt(0)" ::: "memory");
        __builtin_amdgcn_sched_barrier(0);
#pragma unroll
        for (int i = 0; i < 4; ++i) {
          int row = l4 * 4 + i;
          int g = base + row;
#pragma unroll
          for (int f = 0; f < 8; ++f) {
            int e = f * 16 + l15;
            unsigned short val = f2bu(acco[f][i] + b2v[e] + tw1);
            h_lds[row * 128 + (e ^ ((row & 7) << 3))] = val;
            if (g < cS) {
              int nd = sorted[l * NPL_ + start + g];
              sd[(size_t)(m * ND_ + l * NPL_ + nd) * D_ + e] = val;
            }
          }
        }
        asm volatile("s_waitcnt lgkmcnt(0)" ::: "memory");
        __builtin_amdgcn_sched_barrier(0);
        // fused eval
        f32x4 ae[8];
#pragma unroll
        for (int f = 0; f < 8; ++f) ae[f] = (f32x4){0.f, 0.f, 0.f, 0.f};
#pragma unroll
        for (int kc = 0; kc < 4; ++kc) {
          int d0 = kc * 32 + l4 * 8;
          bf16x8 a2 = ldb8(&h_lds[l15 * 128 + (d0 ^ ((l15 & 7) << 3))]);
#pragma unroll
          for (int f = 0; f < 8; ++f) {
            bf16x8 b = ldb8(&we1b[(f * 16 + l15) * D_ + d0]);
            ae[f] = __builtin_amdgcn_mfma_f32_16x16x32_bf16(a2, b, ae[f], 0, 0, 0);
          }
        }
        float part[4] = {0.f, 0.f, 0.f, 0.f};
#pragma unroll
        for (int f = 0; f < 8; ++f) {
          int e = f * 16 + l15;
          float bb = be1[m * D_ + e];
          float wv = we2[m * D_ + e];
#pragma unroll
          for (int i = 0; i < 4; ++i) {
            float he = ae[f][i] + bb;
            he = he > 0.f ? he : 0.f;
            part[i] += he * wv;
          }
        }
#pragma unroll
        for (int mask = 1; mask < 16; mask <<= 1) {
#pragma unroll
          for (int i = 0; i < 4; ++i) part[i] += __shfl_xor(part[i], mask, 64);
        }
        if (l15 == 0) {
#pragma unroll
          for (int i = 0; i < 4; ++i) {
            int g = base + l4 * 4 + i;
            if (g < cS) {
              int nd = sorted[l * NPL_ + start + g];
              int grow = NI_ + l * NPL_ + nd;
              float logit = part[i] + bev + tw0;
              float p_ = pos[grow], n_ = neg[grow];
              float lse = log1pf(__expf(-fabsf(logit)));
              v6[0] += p_ * (fmaxf(-logit, 0.f) + lse);
              v6[1] += n_ * (fmaxf(logit, 0.f) + lse);
              if (logit >= 0.f) v6[2] += p_; else v6[3] += n_;
            }
          }
        }
      }
    }
    __syncthreads();   // layer barrier: sd rows visible block-wide (same CU)
  }
  // wave-reduce v6, stash per unit
#pragma unroll
  for (int mask = 1; mask < 64; mask <<= 1) {
#pragma unroll
    for (int q = 0; q < 4; ++q) v6[q] += __shfl_xor(v6[q], mask, 64);
  }
  if (lane == 0) {
#pragma unroll
    for (int q = 0; q < 4; ++q) wred[unit][q] = v6[q];
  }
  // finalize: sum partial arrays (fixed order)
  float s6[6] = {0.f, 0.f, 0.f, 0.f, 0.f, 0.f};
  const float* bases[6] = {pA + m * PART4_, pB + m * PART4_,
                           pPok + m * PART4_, pNok + m * PART4_, pTp, pTn};
#pragma unroll
  for (int q = 0; q < 6; ++q) {
    float s = 0.f;
    for (int i = tid; i < PART4_; i += 512) s += bases[q][i];
    s6[q] = s;
  }
#pragma unroll
  for (int mask = 1; mask < 64; mask <<= 1) {
#pragma unroll
    for (int q = 0; q < 6; ++q) s6[q] += __shfl_xor(s6[q], mask, 64);
  }
  if (lane == 0) {
#pragma unroll
    for (int q = 0; q < 6; ++q) fin[unit][q] = s6[q];
  }
  __syncthreads();
  if (tid == 0) {
    float tot[6], slow[4];
#pragma unroll
    for (int q = 0; q < 6; ++q) {
      float s = 0.f;
      for (int u = 0; u < 8; ++u) s += fin[u][q];
      tot[q] = s;
    }
#pragma unroll
    for (int q = 0; q < 4; ++q) {
      float s = 0.f;
      for (int u = 0; u < 8; ++u) s += wred[u][q];
      slow[q] = s;
    }
    float SA = tot[0] + slow[0], SB = tot[1] + slow[1];
    float SPok = tot[2] + slow[2], SNok = tot[3] + slow[3];
    float tp = tot[4], tn = tot[5];
    float pw = tn / tp;
    out[0 + m] = pw * SA + SB;
    out[2 + m] = SPok;
    out[4 + m] = SNok;
    if (m == 0) { out[6] = tp; out[7] = tn; }
  }
}

extern "C" void kernel_launch(void* const* d_in, const int* in_sizes, int n_in,
                              void* d_out, int out_size, void* d_ws, size_t ws_size,
                              hipStream_t stream) {
  const int*   thax = (const int*)d_in[0];
  const float* sine = (const float*)d_in[1];
  const int*   par  = (const int*)d_in[2];
  const int*   ridx = (const int*)d_in[3];
  const float* pos  = (const float*)d_in[4];
  const float* neg  = (const float*)d_in[5];
  const float* init_table = (const float*)d_in[6];
  const float* s_vec = (const float*)d_in[7];
  const float* W1 = (const float*)d_in[8];
  const float* b1 = (const float*)d_in[9];
  const float* W2 = (const float*)d_in[10];
  const float* b2 = (const float*)d_in[11];
  const float* tweaks = (const float*)d_in[12];
  const float* We1 = (const float*)d_in[13];
  const float* be1 = (const float*)d_in[14];
  const float* we2 = (const float*)d_in[15];
  const float* be2 = (const float*)d_in[16];

  char* ws = (char*)d_ws;
  unsigned short* W1T  = (unsigned short*)(ws + OFF_W1T);
  unsigned short* W2T  = (unsigned short*)(ws + OFF_W2T);
  unsigned short* We1T = (unsigned short*)(ws + OFF_WE1T);
  unsigned short* tab  = (unsigned short*)(ws + OFF_TAB);
  unsigned short* svec = (unsigned short*)(ws + OFF_SVEC);
  int* sorted = (int*)(ws + OFF_SORTED);
  int* starts = (int*)(ws + OFF_STARTS);
  int* cntF   = (int*)(ws + OFF_CNTF);
  int* cntA   = (int*)(ws + OFF_CNTA);
  float* EA2  = (float*)(ws + OFF_EA2);
  float* EWB  = (float*)(ws + OFF_EWB);
  float* pA   = (float*)(ws + OFF_PA);
  float* pB   = (float*)(ws + OFF_PB);
  float* pPok = (float*)(ws + OFF_PPOK);
  float* pNok = (float*)(ws + OFF_PNOK);
  float* pTp  = (float*)(ws + OFF_PTP);
  float* pTn  = (float*)(ws + OFF_PTN);
  float* G    = (float*)(ws + OFF_G);
  unsigned short* sd = (unsigned short*)(ws + OFF_STORE);
  int* fsg      = (int*)(ws + OFF_FSG);
  int* cfg      = (int*)(ws + OFF_CFG);
  int* fastlist = (int*)(ws + OFF_FLIST);

  megaprep_kernel<<<1369, 256, 0, stream>>>(
      W1, W2, We1, init_table, s_vec, b1, be1, we2, ridx, par,
      W1T, W2T, We1T, tab, svec, G, EA2, EWB, sorted, starts, cntF, cntA,
      fsg, cfg, fastlist, (unsigned int*)pA);
  main_kernel<<<2306, 256, 0, stream>>>(
      thax, sine, par, pos, neg, b2, tweaks, G, W2T, We1T, EA2, EWB,
      be1, we2, be2, fsg, cfg, fastlist, sd,
      pA, pB, pPok, pNok, pTp, pTn);
  tail_kernel<<<2, 512, 0, stream>>>(
      thax, sine, par, b1, b2, tweaks, pos, neg, be1, we2, be2,
      tab, svec, W1T, W2T, We1T, sorted, starts, cntF, cntA, sd,
      pA, pB, pPok, pNok, pTp, pTn, (float*)d_out);
}

// Round 13
// 234.705 us; speedup vs baseline: 1.5535x; 1.5535x over previous
//
#include <hip/hip_runtime.h>
#include <hip/hip_bf16.h>

#define M_ 2
#define D_ 128
#define NI_ 131072
#define L_ 4
#define NPL_ 2048
#define R_ 8
#define T_ 32
#define N_ (NI_ + L_ * NPL_)   // 139264
#define ND_ (L_ * NPL_)        // 8192 deriv nodes
#define PART5_ 1216            // 512 init + 640 fast + 1 posneg + 48 slowA + pad

typedef __bf16 bf16x8 __attribute__((ext_vector_type(8)));
typedef float f32x4 __attribute__((ext_vector_type(4)));

// ---- ws layout (bytes) ----
#define OFF_W1T    0u            // [M][R][128(d)][256(c)] bf16 = 1048576
#define OFF_W2T    1048576u      // [M][R][128(e)][128(d)] bf16 = 524288
#define OFF_WE1T   1572864u      // [M][128(e)][128(d)] bf16    = 65536
#define OFF_TAB    1638400u      // [M][T][128] bf16            = 16384
#define OFF_SVEC   1654784u      // [M][128] bf16               = 512
#define OFF_EA2    1688448u      // [M][64][32][2] f32          = 32768
#define OFF_EWB    1721216u      // [M][128][2] f32             = 2048
#define OFF_PA     1723264u      // [M][1216] f32 = 9728
#define OFF_PB     1732992u
#define OFF_PPOK   1742720u
#define OFF_PNOK   1752448u
#define OFF_PTP    1762176u      // [1216] f32 = 4864
#define OFF_PTN    1767040u
#define OFF_G      1771904u      // [M][R][2][33][128] f32 = 540672
#define OFF_STORE  2312576u      // [M][8192][128] bf16 = 4194304
#define OFF_FSG    6506880u      // [8] int
#define OFF_CFG    6506912u      // [8] int
#define OFF_FLIST  6506944u      // [8192] int
#define OFF_SAL    6539712u      // [8192] int slowA list (rule-sorted)
#define OFF_SBL    6572480u      // [512] int slowB list ((l,r)-sorted)
#define OFF_FSGA   6574528u      // [8] int
#define OFF_CFGA   6574560u      // [8] int
#define OFF_CB24   6574592u      // [24] int slowB counts per (l-1, r)
#define OFF_OB24   6574688u      // [24] int slowB offsets ; end ~6.57MB

__device__ __forceinline__ unsigned short f2bu(float f) {
  unsigned int u = __float_as_uint(f);
  u += 0x7fffu + ((u >> 16) & 1u);        // RNE (finite values only)
  return (unsigned short)(u >> 16);
}
__device__ __forceinline__ bf16x8 ldb8(const unsigned short* p) {
  return *reinterpret_cast<const bf16x8*>(p);
}

// value of node `row` (global id), 8 dims from d0 (slow paths only).
__device__ __forceinline__ bf16x8 node_chunk(int m, int row, int d0,
    const unsigned short* tab, const unsigned short* svec,
    const unsigned short* sd, const int* thax, const float* sine) {
  if (row < NI_) {
    bf16x8 tv = ldb8(&tab[(m * T_ + thax[row]) * D_ + d0]);
    bf16x8 sv = ldb8(&svec[m * D_ + d0]);
    float sn = sine[row];
    bf16x8 r;
#pragma unroll
    for (int j = 0; j < 8; ++j)
      r[j] = (__bf16)((float)tv[j] + sn * (float)sv[j]);
    return r;
  }
  return ldb8(&sd[(size_t)(m * ND_ + (row - NI_)) * D_ + d0]);
}

// ================= mega-prep =================
// jobs: [0,800) transposes; 800 tab/svec; [801,1329) gprep; [1329,1363) eaprep;
//       1363 classify (fast/slowA/slowB) + lists; 1364 zero partials.
__global__ __launch_bounds__(256) void megaprep_kernel(
    const float* W1, const float* W2, const float* We1,
    const float* init_table, const float* s_vec,
    const float* b1, const float* be1, const float* we2,
    const int* ridx, const int* par,
    unsigned short* W1T, unsigned short* W2T, unsigned short* We1T,
    unsigned short* tab, unsigned short* svec,
    float* G, float* EA2, float* EWB,
    int* fsg, int* cfg, int* fastlist,
    int* fsgA, int* cfgA, int* slowAlist,
    int* cB24, int* oB24, int* slowBlist, unsigned int* pzero) {
  __shared__ float smem[1056];
  __shared__ unsigned int fbm[256];
  __shared__ int scnt[40], soff[40];
  int job = blockIdx.x;
  int tid = threadIdx.x;

  if (job < 800) {                       // -------- transposes --------
    int z, rblk, cblk;
    if (job < 512)      { z = job >> 5;            rblk = (job & 31) >> 2; cblk = job & 3; }
    else if (job < 768) { int q = job - 512; z = 16 + (q >> 4); rblk = (q & 15) >> 2; cblk = q & 3; }
    else                { int q = job - 768; z = 32 + (q >> 4); rblk = (q & 15) >> 2; cblk = q & 3; }
    const float* src; unsigned short* dst; int R;
    if (z < 16)      { src = W1  + (size_t)z * 32768;        dst = W1T  + (size_t)z * 32768;        R = 256; }
    else if (z < 32) { src = W2  + (size_t)(z - 16) * 16384; dst = W2T  + (size_t)(z - 16) * 16384; R = 128; }
    else             { src = We1 + (size_t)(z - 32) * 16384; dst = We1T + (size_t)(z - 32) * 16384; R = 128; }
    int r0 = rblk * 32, c0 = cblk * 32;
    float (*tile)[33] = (float(*)[33])smem;
    int tx = tid & 31, ty = tid >> 5;
#pragma unroll
    for (int k = 0; k < 4; ++k)
      tile[ty + 8 * k][tx] = src[(size_t)(r0 + ty + 8 * k) * D_ + c0 + tx];
    __syncthreads();
#pragma unroll
    for (int k = 0; k < 4; ++k)
      dst[(size_t)(c0 + ty + 8 * k) * R + r0 + tx] = f2bu(tile[tx][ty + 8 * k]);
  } else if (job == 800) {               // -------- tab/svec convert --------
    for (int i = tid; i < 8448; i += 256) {
      if (i < 8192) tab[i] = f2bu(init_table[i]);
      else svec[i - 8192] = f2bu(s_vec[i - 8192]);
    }
  } else if (job < 1329) {               // -------- gprep: G[m][r][slot][t][e] --------
    int q = job - 801;
    int t = q / 16, mr = q & 15;         // t in [0,32], 32 == svec row
    int m = mr >> 3;
    int slot = tid >> 7, e = tid & 127;
    const float* vec = (t < 32) ? &init_table[(size_t)(m * T_ + t) * D_]
                                : &s_vec[(size_t)m * D_];
    if (tid < 128) smem[tid] = vec[tid];
    __syncthreads();
    const float* w = &W1[((size_t)mr * 256 + slot * 128) * D_];
    float acc = 0.f;
#pragma unroll 8
    for (int c = 0; c < 128; ++c) acc = fmaf(smem[c], w[c * D_ + e], acc);
    if (slot == 0 && t < 32) acc += b1[mr * D_ + e];   // fold b1 into slot-a rows
    G[((size_t)(mr * 2 + slot) * 33 + t) * D_ + e] = acc;
  } else if (job < 1363) {               // -------- eaprep: eval-init tables --------
    int q = job - 1329;
    int m = q / 17, t = (q % 17) * 2 + (tid >> 7);
    int e = tid & 127;
    if (t <= 32) {
      const float* vec = (t < 32) ? &init_table[(size_t)(m * T_ + t) * D_]
                                  : &s_vec[(size_t)m * D_];
      const float* w = &We1[(size_t)m * D_ * D_];
      float acc = 0.f;
#pragma unroll 8
      for (int d = 0; d < 128; ++d) acc = fmaf(vec[d], w[d * D_ + e], acc);
      if (t < 32) {
        EA2[m * 4096 + ((e >> 1) * 32 + t) * 2 + (e & 1)] = acc + be1[m * D_ + e];
      } else {
        EWB[(m * D_ + e) * 2 + 0] = acc;
        EWB[(m * D_ + e) * 2 + 1] = we2[m * D_ + e];
      }
    }
  } else if (job == 1363) {              // -------- classify + lists --------
    for (int i = tid; i < 256; i += 256) fbm[i] = 0u;
    for (int i = tid; i < 40; i += 256) scnt[i] = 0;
    __syncthreads();
    for (int g = tid; g < ND_; g += 256) {
      if (par[2 * g] < NI_ && par[2 * g + 1] < NI_)
        atomicOr(&fbm[g >> 5], 1u << (g & 31));
    }
    __syncthreads();
    for (int g = tid; g < ND_; g += 256) {
      int r = ridx[g];
      int f = (fbm[g >> 5] >> (g & 31)) & 1;
      if (f) atomicAdd(&scnt[r], 1);
      else {
        int p0 = par[2 * g], p1 = par[2 * g + 1];
        int a0 = p0 < NI_ || ((fbm[(p0 - NI_) >> 5] >> ((p0 - NI_) & 31)) & 1);
        int a1 = p1 < NI_ || ((fbm[(p1 - NI_) >> 5] >> ((p1 - NI_) & 31)) & 1);
        if (a0 && a1) atomicAdd(&scnt[8 + r], 1);
        else atomicAdd(&scnt[16 + ((g >> 11) - 1) * 8 + r], 1);
      }
    }
    __syncthreads();
    if (tid == 0) {
      int run = 0;
      for (int r = 0; r < 8; ++r) { soff[r] = run; fsg[r] = run; cfg[r] = scnt[r]; run += scnt[r]; }
      run = 0;
      for (int r = 0; r < 8; ++r) { soff[8 + r] = run; fsgA[r] = run; cfgA[r] = scnt[8 + r]; run += scnt[8 + r]; }
      run = 0;
      for (int b = 0; b < 24; ++b) { soff[16 + b] = run; oB24[b] = run; cB24[b] = scnt[16 + b]; run += scnt[16 + b]; }
    }
    __syncthreads();
    for (int g = tid; g < ND_; g += 256) {
      int r = ridx[g];
      int f = (fbm[g >> 5] >> (g & 31)) & 1;
      if (f) fastlist[atomicAdd(&soff[r], 1)] = g;
      else {
        int p0 = par[2 * g], p1 = par[2 * g + 1];
        int a0 = p0 < NI_ || ((fbm[(p0 - NI_) >> 5] >> ((p0 - NI_) & 31)) & 1);
        int a1 = p1 < NI_ || ((fbm[(p1 - NI_) >> 5] >> ((p1 - NI_) & 31)) & 1);
        if (a0 && a1) slowAlist[atomicAdd(&soff[8 + r], 1)] = g;
        else slowBlist[atomicAdd(&soff[16 + ((g >> 11) - 1) * 8 + r], 1)] = g;
      }
    }
  } else {                               // -------- zero partial arrays --------
    for (int i = tid; i < 12160; i += 256) pzero[i] = 0u;
  }
}

// ================= main: fast rows (+fused eval) + eval-init + deriv pos/neg ====
// grid 2306. bid<1280: fast tile. bid<2304: eval-init. bid>=2304: deriv pos/neg sum.
__global__ __launch_bounds__(256) void main_kernel(
    const int* thax, const float* sine, const int* par,
    const float* pos, const float* neg,
    const float* b2, const float* tweaks,
    const float* G, const unsigned short* W2T, const unsigned short* We1T,
    const float* EA2, const float* EWB,
    const float* be1, const float* we2, const float* be2,
    const int* fsg, const int* cfg, const int* fastlist,
    unsigned short* sd,
    float* pA, float* pB, float* pPok, float* pNok, float* pTp, float* pTn) {
  __shared__ float sbuf[4448];
  int bid = blockIdx.x;
  int tid = threadIdx.x;
  int w = tid >> 6, lane = tid & 63;

  if (bid < 1280) {                       // ---------- fast rows ----------
    int m = bid / 640, q = bid % 640;
    int r = q / 80, tile = q % 80;
    int cnt = cfg[r];
    int base = tile * 16;
    if (base >= cnt) return;
    unsigned short* h_lds = (unsigned short*)sbuf;       // [16][128] bf16
    int*   t0a  = (int*)(sbuf + 1024);
    int*   t1a  = t0a + 16;
    float* s0a  = (float*)(t1a + 16);
    float* s1a  = s0a + 16;
    int*   gida = (int*)(s1a + 16);
    float* red2 = sbuf + 1104;                           // [4][16]
    if (tid < 16) {
      int loc = base + tid; if (loc >= cnt) loc = cnt - 1;
      int gid = fastlist[fsg[r] + loc];
      int p0 = par[2 * gid], p1 = par[2 * gid + 1];
      t0a[tid] = thax[p0]; s0a[tid] = sine[p0];
      t1a[tid] = thax[p1]; s1a[tid] = sine[p1];
      gida[tid] = gid;
    }
    __syncthreads();
    const float* Gm = &G[(size_t)(m * R_ + r) * 8448];
    {                                     // coop-build h (1 thread = row x 8 dims)
      int row = tid >> 4, seg = tid & 15, d0 = seg * 8;
      int t0 = t0a[row], t1 = t1a[row];
      float s0 = s0a[row], s1 = s1a[row];
      const float* pa = &Gm[t0 * 128 + d0];
      const float* pb = &Gm[(33 + t1) * 128 + d0];
      const float* pu = &Gm[4096 + d0];
      const float* pv = &Gm[8320 + d0];
      bf16x8 hv;
#pragma unroll
      for (int half = 0; half < 2; ++half) {
        float4 a = *(const float4*)(pa + half * 4);
        float4 b = *(const float4*)(pb + half * 4);
        float4 u = *(const float4*)(pu + half * 4);
        float4 v = *(const float4*)(pv + half * 4);
        hv[half * 4 + 0] = (__bf16)fmaxf(a.x + b.x + s0 * u.x + s1 * v.x, 0.f);
        hv[half * 4 + 1] = (__bf16)fmaxf(a.y + b.y + s0 * u.y + s1 * v.y, 0.f);
        hv[half * 4 + 2] = (__bf16)fmaxf(a.z + b.z + s0 * u.z + s1 * v.z, 0.f);
        hv[half * 4 + 3] = (__bf16)fmaxf(a.w + b.w + s0 * u.w + s1 * v.w, 0.f);
      }
      *(bf16x8*)&h_lds[row * 128 + (d0 ^ ((row & 7) << 3))] = hv;
    }
    __syncthreads();
    int l15 = lane & 15, l4 = lane >> 4;  // GEMM2: 4 waves x 2 f each
    const unsigned short* w2b = &W2T[(size_t)(m * R_ + r) * D_ * D_];
    f32x4 acc[2];
    acc[0] = (f32x4){0.f, 0.f, 0.f, 0.f};
    acc[1] = (f32x4){0.f, 0.f, 0.f, 0.f};
#pragma unroll
    for (int kc = 0; kc < 4; ++kc) {
      int d0 = kc * 32 + l4 * 8;
      bf16x8 a2 = ldb8(&h_lds[l15 * 128 + (d0 ^ ((l15 & 7) << 3))]);
#pragma unroll
      for (int f = 0; f < 2; ++f) {
        int fg = w * 2 + f;
        bf16x8 b = ldb8(&w2b[(fg * 16 + l15) * D_ + d0]);
        acc[f] = __builtin_amdgcn_mfma_f32_16x16x32_bf16(a2, b, acc[f], 0, 0, 0);
      }
    }
    float tw1 = tweaks[m * 2 + 1];
    const float* b2v = &b2[(m * R_ + r) * D_];
    __syncthreads();                      // done reading h_lds (GEMM2)
#pragma unroll
    for (int i = 0; i < 4; ++i) {
      int row = l4 * 4 + i;
      int g = base + row;
#pragma unroll
      for (int f = 0; f < 2; ++f) {
        int e = (w * 2 + f) * 16 + l15;
        unsigned short val = f2bu(acc[f][i] + b2v[e] + tw1);
        h_lds[row * 128 + (e ^ ((row & 7) << 3))] = val;
        if (g < cnt) sd[(size_t)(m * ND_ + gida[row]) * D_ + e] = val;
      }
    }
    __syncthreads();
    // fused eval: out @ We1 -> relu -> we2
    f32x4 ae[2];
    ae[0] = (f32x4){0.f, 0.f, 0.f, 0.f};
    ae[1] = (f32x4){0.f, 0.f, 0.f, 0.f};
    const unsigned short* we1b = &We1T[(size_t)m * D_ * D_];
#pragma unroll
    for (int kc = 0; kc < 4; ++kc) {
      int d0 = kc * 32 + l4 * 8;
      bf16x8 a2 = ldb8(&h_lds[l15 * 128 + (d0 ^ ((l15 & 7) << 3))]);
#pragma unroll
      for (int f = 0; f < 2; ++f) {
        int fg = w * 2 + f;
        bf16x8 b = ldb8(&we1b[(fg * 16 + l15) * D_ + d0]);
        ae[f] = __builtin_amdgcn_mfma_f32_16x16x32_bf16(a2, b, ae[f], 0, 0, 0);
      }
    }
    float part[4] = {0.f, 0.f, 0.f, 0.f};
#pragma unroll
    for (int f = 0; f < 2; ++f) {
      int e = (w * 2 + f) * 16 + l15;
      float bb = be1[m * D_ + e];
      float wv = we2[m * D_ + e];
#pragma unroll
      for (int i = 0; i < 4; ++i) {
        float he = ae[f][i] + bb;
        he = he > 0.f ? he : 0.f;
        part[i] += he * wv;
      }
    }
#pragma unroll
    for (int mask = 1; mask < 16; mask <<= 1) {
#pragma unroll
      for (int i = 0; i < 4; ++i) part[i] += __shfl_xor(part[i], mask, 64);
    }
    if (l15 == 0) {
#pragma unroll
      for (int i = 0; i < 4; ++i) red2[w * 16 + l4 * 4 + i] = part[i];
    }
    __syncthreads();
    if (tid < 16) {
      int g = base + tid;
      float v6[4] = {0.f, 0.f, 0.f, 0.f};
      if (g < cnt) {
        float logit = red2[tid] + red2[16 + tid] + red2[32 + tid] + red2[48 + tid]
                    + be2[m] + tweaks[m * 2 + 0];
        int grow = NI_ + gida[tid];
        float p_ = pos[grow], n_ = neg[grow];
        float lse = log1pf(__expf(-fabsf(logit)));
        v6[0] = p_ * (fmaxf(-logit, 0.f) + lse);
        v6[1] = n_ * (fmaxf(logit, 0.f) + lse);
        v6[2] = logit >= 0.f ? p_ : 0.f;
        v6[3] = logit < 0.f ? n_ : 0.f;
      }
#pragma unroll
      for (int mask = 1; mask < 16; mask <<= 1) {
#pragma unroll
        for (int qq = 0; qq < 4; ++qq) v6[qq] += __shfl_xor(v6[qq], mask, 64);
      }
      if (tid == 0) {
        int slot = 512 + r * 80 + tile;
        pA[m * PART5_ + slot] = v6[0];
        pB[m * PART5_ + slot] = v6[1];
        pPok[m * PART5_ + slot] = v6[2];
        pNok[m * PART5_ + slot] = v6[3];
      }
    }
  } else if (bid < 2304) {                // ---------- eval-init ----------
    int q = bid - 1280;
    int m = q >> 9, xb = q & 511;
    float* lea = sbuf;                    // [p=64][t=32][2]
    float* lwb = sbuf + 4096;             // [e=128][{EB,we2}]
    float* red = sbuf + 4352;
    for (int i = tid; i < 4096; i += 256) lea[i] = EA2[m * 4096 + i];
    if (tid < 256) lwb[tid] = EWB[m * 256 + tid];
    __syncthreads();
    int row = xb * 256 + tid;
    int t = thax[row];
    float s = sine[row];
    float acc = 0.f;
#pragma unroll 8
    for (int p = 0; p < 64; ++p) {
      float2 ea = *(const float2*)&lea[(p * 32 + t) * 2];
      float4 wb = *(const float4*)&lwb[p * 4];
      float x0 = fmaf(s, wb.x, ea.x); x0 = fmaxf(x0, 0.f);
      acc = fmaf(x0, wb.y, acc);
      float x1 = fmaf(s, wb.z, ea.y); x1 = fmaxf(x1, 0.f);
      acc = fmaf(x1, wb.w, acc);
    }
    float logit = acc + be2[m] + tweaks[m * 2 + 0];
    float p_ = pos[row], n_ = neg[row];
    float lse = log1pf(__expf(-fabsf(logit)));
    float v[6];
    v[0] = p_ * (fmaxf(-logit, 0.f) + lse);
    v[1] = n_ * (fmaxf(logit, 0.f) + lse);
    v[2] = logit >= 0.f ? p_ : 0.f;
    v[3] = logit < 0.f ? n_ : 0.f;
    v[4] = p_; v[5] = n_;
#pragma unroll
    for (int mask = 1; mask < 64; mask <<= 1) {
#pragma unroll
      for (int k = 0; k < 6; ++k) v[k] += __shfl_xor(v[k], mask, 64);
    }
    if (lane == 0) {
#pragma unroll
      for (int k = 0; k < 6; ++k) red[k * 16 + w] = v[k];
    }
    __syncthreads();
    if (tid == 0) {
      float t6[6];
#pragma unroll
      for (int k = 0; k < 6; ++k)
        t6[k] = red[k * 16 + 0] + red[k * 16 + 1] + red[k * 16 + 2] + red[k * 16 + 3];
      pA[m * PART5_ + xb] = t6[0];
      pB[m * PART5_ + xb] = t6[1];
      pPok[m * PART5_ + xb] = t6[2];
      pNok[m * PART5_ + xb] = t6[3];
      if (m == 0) { pTp[xb] = t6[4]; pTn[xb] = t6[5]; }
    }
  } else {                                // ---------- deriv pos/neg total ----------
    int j = bid - 2304;                   // 0: pos, 1: neg
    float* red = sbuf;
    const float* src = j ? neg : pos;
    float s = 0.f;
    for (int i = NI_ + tid; i < N_; i += 256) s += src[i];
#pragma unroll
    for (int mask = 1; mask < 64; mask <<= 1) s += __shfl_xor(s, mask, 64);
    if (lane == 0) red[w] = s;
    __syncthreads();
    if (tid == 0) {
      float t = red[0] + red[1] + red[2] + red[3];
      if (j == 0) pTp[1152] = t; else pTn[1152] = t;
    }
  }
}

// ================= slowA: all-layer slow rows with fast/init parents ===========
// grid (6, 8, 2), 128 threads (2 waves, f-split 4+4). Parents ready after main.
__global__ __launch_bounds__(128) void slowA_kernel(
    const int* thax, const float* sine, const int* par,
    const float* b1, const float* b2, const float* tweaks,
    const float* pos, const float* neg,
    const float* be1, const float* we2, const float* be2,
    const unsigned short* tab, const unsigned short* svec,
    const unsigned short* W1T, const unsigned short* W2T,
    const unsigned short* We1T,
    const int* fsgA, const int* cfgA, const int* slowAlist,
    unsigned short* sd,
    float* pA, float* pB, float* pPok, float* pNok) {
  int tile = blockIdx.x, r = blockIdx.y, m = blockIdx.z;
  int cnt = cfgA[r];
  int base = tile * 16;
  if (base >= cnt) return;
  int start = fsgA[r];
  int tid = threadIdx.x;
  int w = tid >> 6, lane = tid & 63;
  int l15 = lane & 15, l4 = lane >> 4;
  __shared__ unsigned short h_lds[16 * 128];
  __shared__ float red2[32];
  __shared__ int grows[16];

  if (tid < 16) {
    int loc = base + tid; if (loc >= cnt) loc = cnt - 1;
    grows[tid] = slowAlist[start + loc];
  }
  __syncthreads();
  int g0 = grows[l15];
  int p0 = par[2 * g0], p1 = par[2 * g0 + 1];
  const unsigned short* w1b = &W1T[(size_t)(m * R_ + r) * D_ * 256];
  const unsigned short* w2b = &W2T[(size_t)(m * R_ + r) * D_ * D_];
  const unsigned short* we1b = &We1T[(size_t)m * D_ * D_];

  bf16x8 av[8];
#pragma unroll
  for (int kc = 0; kc < 8; ++kc) {
    int k = kc * 32 + l4 * 8;
    int p = (k < 128) ? p0 : p1;
    av[kc] = node_chunk(m, p, k & 127, tab, svec, sd, thax, sine);
  }
  f32x4 acch[4];
#pragma unroll
  for (int f = 0; f < 4; ++f) acch[f] = (f32x4){0.f, 0.f, 0.f, 0.f};
#pragma unroll
  for (int kc = 0; kc < 8; ++kc) {
    int k = kc * 32 + l4 * 8;
#pragma unroll
    for (int f = 0; f < 4; ++f) {
      int fg = w * 4 + f;
      bf16x8 b = ldb8(&w1b[(fg * 16 + l15) * 256 + k]);
      acch[f] = __builtin_amdgcn_mfma_f32_16x16x32_bf16(av[kc], b, acch[f], 0, 0, 0);
    }
  }
  const float* b1v = &b1[(m * R_ + r) * D_];
#pragma unroll
  for (int f = 0; f < 4; ++f) {
    int d = (w * 4 + f) * 16 + l15;
    float bb = b1v[d];
#pragma unroll
    for (int i = 0; i < 4; ++i) {
      int row = l4 * 4 + i;
      float h = acch[f][i] + bb;
      h = h > 0.f ? h : 0.f;
      h_lds[row * 128 + (d ^ ((row & 7) << 3))] = f2bu(h);
    }
  }
  __syncthreads();
  f32x4 acco[4];
#pragma unroll
  for (int f = 0; f < 4; ++f) acco[f] = (f32x4){0.f, 0.f, 0.f, 0.f};
#pragma unroll
  for (int kc = 0; kc < 4; ++kc) {
    int d0 = kc * 32 + l4 * 8;
    bf16x8 a2 = ldb8(&h_lds[l15 * 128 + (d0 ^ ((l15 & 7) << 3))]);
#pragma unroll
    for (int f = 0; f < 4; ++f) {
      int fg = w * 4 + f;
      bf16x8 b = ldb8(&w2b[(fg * 16 + l15) * D_ + d0]);
      acco[f] = __builtin_amdgcn_mfma_f32_16x16x32_bf16(a2, b, acco[f], 0, 0, 0);
    }
  }
  float tw1 = tweaks[m * 2 + 1];
  const float* b2v = &b2[(m * R_ + r) * D_];
  __syncthreads();
#pragma unroll
  for (int i = 0; i < 4; ++i) {
    int row = l4 * 4 + i;
    int g = base + row;
#pragma unroll
    for (int f = 0; f < 4; ++f) {
      int e = (w * 4 + f) * 16 + l15;
      unsigned short val = f2bu(acco[f][i] + b2v[e] + tw1);
      h_lds[row * 128 + (e ^ ((row & 7) << 3))] = val;
      if (g < cnt) sd[(size_t)(m * ND_ + grows[row]) * D_ + e] = val;
    }
  }
  __syncthreads();
  f32x4 ae[4];
#pragma unroll
  for (int f = 0; f < 4; ++f) ae[f] = (f32x4){0.f, 0.f, 0.f, 0.f};
#pragma unroll
  for (int kc = 0; kc < 4; ++kc) {
    int d0 = kc * 32 + l4 * 8;
    bf16x8 a2 = ldb8(&h_lds[l15 * 128 + (d0 ^ ((l15 & 7) << 3))]);
#pragma unroll
    for (int f = 0; f < 4; ++f) {
      int fg = w * 4 + f;
      bf16x8 b = ldb8(&we1b[(fg * 16 + l15) * D_ + d0]);
      ae[f] = __builtin_amdgcn_mfma_f32_16x16x32_bf16(a2, b, ae[f], 0, 0, 0);
    }
  }
  float part[4] = {0.f, 0.f, 0.f, 0.f};
#pragma unroll
  for (int f = 0; f < 4; ++f) {
    int e = (w * 4 + f) * 16 + l15;
    float bb = be1[m * D_ + e];
    float wv = we2[m * D_ + e];
#pragma unroll
    for (int i = 0; i < 4; ++i) {
      float he = ae[f][i] + bb;
      he = he > 0.f ? he : 0.f;
      part[i] += he * wv;
    }
  }
#pragma unroll
  for (int mask = 1; mask < 16; mask <<= 1) {
#pragma unroll
    for (int i = 0; i < 4; ++i) part[i] += __shfl_xor(part[i], mask, 64);
  }
  if (l15 == 0) {
#pragma unroll
    for (int i = 0; i < 4; ++i) red2[w * 16 + l4 * 4 + i] = part[i];
  }
  __syncthreads();
  if (tid < 16) {
    int g = base + tid;
    float v6[4] = {0.f, 0.f, 0.f, 0.f};
    if (g < cnt) {
      float logit = red2[tid] + red2[16 + tid] + be2[m] + tweaks[m * 2 + 0];
      int grow = NI_ + grows[tid];
      float p_ = pos[grow], n_ = neg[grow];
      float lse = log1pf(__expf(-fabsf(logit)));
      v6[0] = p_ * (fmaxf(-logit, 0.f) + lse);
      v6[1] = n_ * (fmaxf(logit, 0.f) + lse);
      v6[2] = logit >= 0.f ? p_ : 0.f;
      v6[3] = logit < 0.f ? n_ : 0.f;
    }
#pragma unroll
    for (int mask = 1; mask < 16; mask <<= 1) {
#pragma unroll
      for (int qq = 0; qq < 4; ++qq) v6[qq] += __shfl_xor(v6[qq], mask, 64);
    }
    if (tid == 0) {
      int slot = 1153 + r * 6 + tile;
      pA[m * PART5_ + slot] = v6[0];
      pB[m * PART5_ + slot] = v6[1];
      pPok[m * PART5_ + slot] = v6[2];
      pNok[m * PART5_ + slot] = v6[3];
    }
  }
}

// ================= slowB (chained slow rows, ~15) + finalize — ONE block ========
// 512 threads = 8 single-wave tile units; layers ordered by __syncthreads +
// __threadfence_block (block scope, same CU — cheap).
__global__ __launch_bounds__(512) void slowB_kernel(
    const int* thax, const float* sine, const int* par,
    const float* b1, const float* b2, const float* tweaks,
    const float* pos, const float* neg,
    const float* be1, const float* we2, const float* be2,
    const unsigned short* tab, const unsigned short* svec,
    const unsigned short* W1T, const unsigned short* W2T,
    const unsigned short* We1T,
    const int* cB24, const int* oB24, const int* slowBlist,
    unsigned short* sd,
    const float* pA, const float* pB, const float* pPok, const float* pNok,
    const float* pTp, const float* pTn, float* out) {
  __shared__ unsigned short h_all[8][2048];
  __shared__ float accm[2][8][4];
  __shared__ float fin[8][6];
  int tid = threadIdx.x;
  int unit = tid >> 6, lane = tid & 63;
  int l15 = lane & 15, l4 = lane >> 4;
  unsigned short* h_lds = h_all[unit];
  if (lane == 0) {
#pragma unroll
    for (int q = 0; q < 4; ++q) { accm[0][unit][q] = 0.f; accm[1][unit][q] = 0.f; }
  }
  float v6[2][4] = {{0.f,0.f,0.f,0.f},{0.f,0.f,0.f,0.f}};

#pragma unroll
  for (int m = 0; m < 2; ++m) {
    float tw1 = tweaks[m * 2 + 1], tw0 = tweaks[m * 2 + 0], bev = be2[m];
    const unsigned short* we1b = &We1T[(size_t)m * D_ * D_];
    for (int l = 1; l < L_; ++l) {
      int tcount = 0;
      for (int r = 0; r < R_; ++r) {
        int bkt = (l - 1) * 8 + r;
        int cnt = cB24[bkt], off = oB24[bkt];
        int nt = (cnt + 15) >> 4;
        const unsigned short* w1b = &W1T[(size_t)(m * R_ + r) * D_ * 256];
        const unsigned short* w2b = &W2T[(size_t)(m * R_ + r) * D_ * D_];
        const float* b1v = &b1[(m * R_ + r) * D_];
        const float* b2v = &b2[(m * R_ + r) * D_];
        for (int t = 0; t < nt; ++t, ++tcount) {
          if ((tcount & 7) != unit) continue;
          int base = t * 16;
          int loc = base + l15; if (loc >= cnt) loc = cnt - 1;
          int g0 = slowBlist[off + loc];
          int p0 = par[2 * g0], p1 = par[2 * g0 + 1];
          bf16x8 av[8];
#pragma unroll
          for (int kc = 0; kc < 8; ++kc) {
            int k = kc * 32 + l4 * 8;
            int p = (k < 128) ? p0 : p1;
            av[kc] = node_chunk(m, p, k & 127, tab, svec, sd, thax, sine);
          }
          f32x4 acch[8];
#pragma unroll
          for (int f = 0; f < 8; ++f) acch[f] = (f32x4){0.f, 0.f, 0.f, 0.f};
#pragma unroll
          for (int kc = 0; kc < 8; ++kc) {
            int k = kc * 32 + l4 * 8;
#pragma unroll
            for (int f = 0; f < 8; ++f) {
              bf16x8 b = ldb8(&w1b[(f * 16 + l15) * 256 + k]);
              acch[f] = __builtin_amdgcn_mfma_f32_16x16x32_bf16(av[kc], b, acch[f], 0, 0, 0);
            }
          }
#pragma unroll
          for (int f = 0; f < 8; ++f) {
            int d = f * 16 + l15;
            float bb = b1v[d];
#pragma unroll
            for (int i = 0; i < 4; ++i) {
              int row = l4 * 4 + i;
              float h = acch[f][i] + bb;
              h = h > 0.f ? h : 0.f;
              h_lds[row * 128 + (d ^ ((row & 7) << 3))] = f2bu(h);
            }
          }
          asm volatile("s_waitcnt lgkmcnt(0)" ::: "memory");
          __builtin_amdgcn_sched_barrier(0);
          f32x4 acco[8];
#pragma unroll
          for (int f = 0; f < 8; ++f) acco[f] = (f32x4){0.f, 0.f, 0.f, 0.f};
#pragma unroll
          for (int kc = 0; kc < 4; ++kc) {
            int d0 = kc * 32 + l4 * 8;
            bf16x8 a2 = ldb8(&h_lds[l15 * 128 + (d0 ^ ((l15 & 7) << 3))]);
#pragma unroll
            for (int f = 0; f < 8; ++f) {
              bf16x8 b = ldb8(&w2b[(f * 16 + l15) * D_ + d0]);
              acco[f] = __builtin_amdgcn_mfma_f32_16x16x32_bf16(a2, b, acco[f], 0, 0, 0);
            }
          }
          asm volatile("s_waitcnt lgkmcnt(0)" ::: "memory");
          __builtin_amdgcn_sched_barrier(0);
#pragma unroll
          for (int i = 0; i < 4; ++i) {
            int row = l4 * 4 + i;
            int g = base + row;
#pragma unroll
            for (int f = 0; f < 8; ++f) {
              int e = f * 16 + l15;
              unsigned short val = f2bu(acco[f][i] + b2v[e] + tw1);
              h_lds[row * 128 + (e ^ ((row & 7) << 3))] = val;
              if (g < cnt) {
                int gd = slowBlist[off + g];
                sd[(size_t)(m * ND_ + gd) * D_ + e] = val;
              }
            }
          }
          asm volatile("s_waitcnt lgkmcnt(0)" ::: "memory");
          __builtin_amdgcn_sched_barrier(0);
          f32x4 ae[8];
#pragma unroll
          for (int f = 0; f < 8; ++f) ae[f] = (f32x4){0.f, 0.f, 0.f, 0.f};
#pragma unroll
          for (int kc = 0; kc < 4; ++kc) {
            int d0 = kc * 32 + l4 * 8;
            bf16x8 a2 = ldb8(&h_lds[l15 * 128 + (d0 ^ ((l15 & 7) << 3))]);
#pragma unroll
            for (int f = 0; f < 8; ++f) {
              bf16x8 b = ldb8(&we1b[(f * 16 + l15) * D_ + d0]);
              ae[f] = __builtin_amdgcn_mfma_f32_16x16x32_bf16(a2, b, ae[f], 0, 0, 0);
            }
          }
          float part[4] = {0.f, 0.f, 0.f, 0.f};
#pragma unroll
          for (int f = 0; f < 8; ++f) {
            int e = f * 16 + l15;
            float bb = be1[m * D_ + e];
            float wv = we2[m * D_ + e];
#pragma unroll
            for (int i = 0; i < 4; ++i) {
              float he = ae[f][i] + bb;
              he = he > 0.f ? he : 0.f;
              part[i] += he * wv;
            }
          }
#pragma unroll
          for (int mask = 1; mask < 16; mask <<= 1) {
#pragma unroll
            for (int i = 0; i < 4; ++i) part[i] += __shfl_xor(part[i], mask, 64);
          }
          if (l15 == 0) {
#pragma unroll
            for (int i = 0; i < 4; ++i) {
              int g = base + l4 * 4 + i;
              if (g < cnt) {
                int gd = slowBlist[off + g];
                int grow = NI_ + gd;
                float logit = part[i] + bev + tw0;
                float p_ = pos[grow], n_ = neg[grow];
                float lse = log1pf(__expf(-fabsf(logit)));
                v6[m][0] += p_ * (fmaxf(-logit, 0.f) + lse);
                v6[m][1] += n_ * (fmaxf(logit, 0.f) + lse);
                if (logit >= 0.f) v6[m][2] += p_; else v6[m][3] += n_;
              }
            }
          }
        }
      }
      __threadfence_block();
      __syncthreads();   // layer barrier: sd rows visible block-wide
    }
  }
  // reduce v6 per wave, stash per unit/model
#pragma unroll
  for (int mask = 1; mask < 64; mask <<= 1) {
#pragma unroll
    for (int q = 0; q < 4; ++q) {
      v6[0][q] += __shfl_xor(v6[0][q], mask, 64);
      v6[1][q] += __shfl_xor(v6[1][q], mask, 64);
    }
  }
  if (lane == 0) {
#pragma unroll
    for (int q = 0; q < 4; ++q) { accm[0][unit][q] = v6[0][q]; accm[1][unit][q] = v6[1][q]; }
  }
  __syncthreads();
  // finalize per model
#pragma unroll
  for (int m = 0; m < 2; ++m) {
    const float* bases[6] = {pA + m * PART5_, pB + m * PART5_,
                             pPok + m * PART5_, pNok + m * PART5_, pTp, pTn};
    float s6[6];
#pragma unroll
    for (int q = 0; q < 6; ++q) {
      float s = 0.f;
      for (int i = tid; i < PART5_; i += 512) s += bases[q][i];
      s6[q] = s;
    }
#pragma unroll
    for (int mask = 1; mask < 64; mask <<= 1) {
#pragma unroll
      for (int q = 0; q < 6; ++q) s6[q] += __shfl_xor(s6[q], mask, 64);
    }
    if (lane == 0) {
#pragma unroll
      for (int q = 0; q < 6; ++q) fin[unit][q] = s6[q];
    }
    __syncthreads();
    if (tid == 0) {
      float tot[6];
#pragma unroll
      for (int q = 0; q < 6; ++q) {
        float s = 0.f;
        for (int u = 0; u < 8; ++u) s += fin[u][q];
        tot[q] = s;
      }
      float sl[4];
#pragma unroll
      for (int q = 0; q < 4; ++q) {
        float s = 0.f;
        for (int u = 0; u < 8; ++u) s += accm[m][u][q];
        sl[q] = s;
      }
      float tp = tot[4], tn = tot[5];
      float pw = tn / tp;
      out[0 + m] = pw * (tot[0] + sl[0]) + (tot[1] + sl[1]);
      out[2 + m] = tot[2] + sl[2];
      out[4 + m] = tot[3] + sl[3];
      if (m == 0) { out[6] = tp; out[7] = tn; }
    }
    __syncthreads();
  }
}

extern "C" void kernel_launch(void* const* d_in, const int* in_sizes, int n_in,
                              void* d_out, int out_size, void* d_ws, size_t ws_size,
                              hipStream_t stream) {
  const int*   thax = (const int*)d_in[0];
  const float* sine = (const float*)d_in[1];
  const int*   par  = (const int*)d_in[2];
  const int*   ridx = (const int*)d_in[3];
  const float* pos  = (const float*)d_in[4];
  const float* neg  = (const float*)d_in[5];
  const float* init_table = (const float*)d_in[6];
  const float* s_vec = (const float*)d_in[7];
  const float* W1 = (const float*)d_in[8];
  const float* b1 = (const float*)d_in[9];
  const float* W2 = (const float*)d_in[10];
  const float* b2 = (const float*)d_in[11];
  const float* tweaks = (const float*)d_in[12];
  const float* We1 = (const float*)d_in[13];
  const float* be1 = (const float*)d_in[14];
  const float* we2 = (const float*)d_in[15];
  const float* be2 = (const float*)d_in[16];

  char* ws = (char*)d_ws;
  unsigned short* W1T  = (unsigned short*)(ws + OFF_W1T);
  unsigned short* W2T  = (unsigned short*)(ws + OFF_W2T);
  unsigned short* We1T = (unsigned short*)(ws + OFF_WE1T);
  unsigned short* tab  = (unsigned short*)(ws + OFF_TAB);
  unsigned short* svec = (unsigned short*)(ws + OFF_SVEC);
  float* EA2  = (float*)(ws + OFF_EA2);
  float* EWB  = (float*)(ws + OFF_EWB);
  float* pA   = (float*)(ws + OFF_PA);
  float* pB   = (float*)(ws + OFF_PB);
  float* pPok = (float*)(ws + OFF_PPOK);
  float* pNok = (float*)(ws + OFF_PNOK);
  float* pTp  = (float*)(ws + OFF_PTP);
  float* pTn  = (float*)(ws + OFF_PTN);
  float* G    = (float*)(ws + OFF_G);
  unsigned short* sd = (unsigned short*)(ws + OFF_STORE);
  int* fsg      = (int*)(ws + OFF_FSG);
  int* cfg      = (int*)(ws + OFF_CFG);
  int* fastlist = (int*)(ws + OFF_FLIST);
  int* slowAlist = (int*)(ws + OFF_SAL);
  int* slowBlist = (int*)(ws + OFF_SBL);
  int* fsgA     = (int*)(ws + OFF_FSGA);
  int* cfgA     = (int*)(ws + OFF_CFGA);
  int* cB24     = (int*)(ws + OFF_CB24);
  int* oB24     = (int*)(ws + OFF_OB24);

  megaprep_kernel<<<1365, 256, 0, stream>>>(
      W1, W2, We1, init_table, s_vec, b1, be1, we2, ridx, par,
      W1T, W2T, We1T, tab, svec, G, EA2, EWB,
      fsg, cfg, fastlist, fsgA, cfgA, slowAlist, cB24, oB24, slowBlist,
      (unsigned int*)pA);
  main_kernel<<<2306, 256, 0, stream>>>(
      thax, sine, par, pos, neg, b2, tweaks, G, W2T, We1T, EA2, EWB,
      be1, we2, be2, fsg, cfg, fastlist, sd,
      pA, pB, pPok, pNok, pTp, pTn);
  slowA_kernel<<<dim3(6, R_, M_), 128, 0, stream>>>(
      thax, sine, par, b1, b2, tweaks, pos, neg, be1, we2, be2,
      tab, svec, W1T, W2T, We1T, fsgA, cfgA, slowAlist, sd,
      pA, pB, pPok, pNok);
  slowB_kernel<<<1, 512, 0, stream>>>(
      thax, sine, par, b1, b2, tweaks, pos, neg, be1, we2, be2,
      tab, svec, W1T, W2T, We1T, cB24, oB24, slowBlist, sd,
      pA, pB, pPok, pNok, pTp, pTn, (float*)d_out);
}

// Round 14
// 108.475 us; speedup vs baseline: 3.3612x; 2.1637x over previous
//
#include <hip/hip_runtime.h>
#include <hip/hip_bf16.h>

#define M_ 2
#define D_ 128
#define NI_ 131072
#define L_ 4
#define NPL_ 2048
#define R_ 8
#define T_ 32
#define N_ (NI_ + L_ * NPL_)   // 139264
#define ND_ (L_ * NPL_)        // 8192 deriv nodes
#define PSTRIDE_ 1280          // per-model partial stride (floats)
#define PUSED_ 1248            // used slots: 512 init + 640 fast + 1 posneg + 48 slowA + 32 slowB

typedef __bf16 bf16x8 __attribute__((ext_vector_type(8)));
typedef float f32x4 __attribute__((ext_vector_type(4)));

// ---- ws layout (bytes) ----
#define OFF_W1T    0u            // [M][R][128(d)][256(c)] bf16 = 1048576
#define OFF_W2T    1048576u      // [M][R][128(e)][128(d)] bf16 = 524288
#define OFF_WE1T   1572864u      // [M][128(e)][128(d)] bf16    = 65536
#define OFF_TAB    1638400u      // [M][T][128] bf16            = 16384
#define OFF_SVEC   1654784u      // [M][128] bf16               = 512
#define OFF_EA2    1688448u      // [M][64][32][2] f32          = 32768
#define OFF_EWB    1721216u      // [M][128][2] f32             = 2048
#define OFF_PA     1723264u      // [2][1280] f32 = 10240
#define OFF_PB     1733504u
#define OFF_PPOK   1743744u
#define OFF_PNOK   1753984u
#define OFF_PTP    1764224u      // [1280] f32 = 5120
#define OFF_PTN    1769344u      // end 1774464  (zero span = 51200 B)
#define OFF_G      1774464u      // [M][R][2][33][128] f32 = 540672
#define OFF_STORE  2315136u      // [M][8192][128] bf16 = 4194304
#define OFF_FSG    6509440u      // [8] int
#define OFF_CFG    6509472u      // [8] int
#define OFF_FLIST  6509504u      // [8192] int
#define OFF_SAL    6542272u      // [8192] int slowA list (rule-sorted)
#define OFF_SBL    6575040u      // [512] int slowB list ((l,r)-sorted)
#define OFF_FSGA   6577088u      // [8] int
#define OFF_CFGA   6577120u      // [8] int
#define OFF_CB24   6577152u      // [24] int slowB counts per (l-1, r)
#define OFF_OB24   6577248u      // [24] int slowB offsets ; end ~6.58MB

__device__ __forceinline__ unsigned short f2bu(float f) {
  unsigned int u = __float_as_uint(f);
  u += 0x7fffu + ((u >> 16) & 1u);        // RNE (finite values only)
  return (unsigned short)(u >> 16);
}
__device__ __forceinline__ bf16x8 ldb8(const unsigned short* p) {
  return *reinterpret_cast<const bf16x8*>(p);
}

// value of node `row` (global id), 8 dims from d0 (slow paths only).
__device__ __forceinline__ bf16x8 node_chunk(int m, int row, int d0,
    const unsigned short* tab, const unsigned short* svec,
    const unsigned short* sd, const int* thax, const float* sine) {
  if (row < NI_) {
    bf16x8 tv = ldb8(&tab[(m * T_ + thax[row]) * D_ + d0]);
    bf16x8 sv = ldb8(&svec[m * D_ + d0]);
    float sn = sine[row];
    bf16x8 r;
#pragma unroll
    for (int j = 0; j < 8; ++j)
      r[j] = (__bf16)((float)tv[j] + sn * (float)sv[j]);
    return r;
  }
  return ldb8(&sd[(size_t)(m * ND_ + (row - NI_)) * D_ + d0]);
}

// ================= mega-prep =================
// jobs: [0,800) transposes; 800 tab/svec; [801,1329) gprep; [1329,1363) eaprep;
//       1363 classify (fast/slowA/slowB) + lists; 1364 zero partials.
__global__ __launch_bounds__(256) void megaprep_kernel(
    const float* W1, const float* W2, const float* We1,
    const float* init_table, const float* s_vec,
    const float* b1, const float* be1, const float* we2,
    const int* ridx, const int* par,
    unsigned short* W1T, unsigned short* W2T, unsigned short* We1T,
    unsigned short* tab, unsigned short* svec,
    float* G, float* EA2, float* EWB,
    int* fsg, int* cfg, int* fastlist,
    int* fsgA, int* cfgA, int* slowAlist,
    int* cB24, int* oB24, int* slowBlist, unsigned int* pzero) {
  __shared__ float smem[1056];
  __shared__ unsigned int fbm[256];
  __shared__ int scnt[40], soff[40];
  int job = blockIdx.x;
  int tid = threadIdx.x;

  if (job < 800) {                       // -------- transposes --------
    int z, rblk, cblk;
    if (job < 512)      { z = job >> 5;            rblk = (job & 31) >> 2; cblk = job & 3; }
    else if (job < 768) { int q = job - 512; z = 16 + (q >> 4); rblk = (q & 15) >> 2; cblk = q & 3; }
    else                { int q = job - 768; z = 32 + (q >> 4); rblk = (q & 15) >> 2; cblk = q & 3; }
    const float* src; unsigned short* dst; int R;
    if (z < 16)      { src = W1  + (size_t)z * 32768;        dst = W1T  + (size_t)z * 32768;        R = 256; }
    else if (z < 32) { src = W2  + (size_t)(z - 16) * 16384; dst = W2T  + (size_t)(z - 16) * 16384; R = 128; }
    else             { src = We1 + (size_t)(z - 32) * 16384; dst = We1T + (size_t)(z - 32) * 16384; R = 128; }
    int r0 = rblk * 32, c0 = cblk * 32;
    float (*tile)[33] = (float(*)[33])smem;
    int tx = tid & 31, ty = tid >> 5;
#pragma unroll
    for (int k = 0; k < 4; ++k)
      tile[ty + 8 * k][tx] = src[(size_t)(r0 + ty + 8 * k) * D_ + c0 + tx];
    __syncthreads();
#pragma unroll
    for (int k = 0; k < 4; ++k)
      dst[(size_t)(c0 + ty + 8 * k) * R + r0 + tx] = f2bu(tile[tx][ty + 8 * k]);
  } else if (job == 800) {               // -------- tab/svec convert --------
    for (int i = tid; i < 8448; i += 256) {
      if (i < 8192) tab[i] = f2bu(init_table[i]);
      else svec[i - 8192] = f2bu(s_vec[i - 8192]);
    }
  } else if (job < 1329) {               // -------- gprep: G[m][r][slot][t][e] --------
    int q = job - 801;
    int t = q / 16, mr = q & 15;         // t in [0,32], 32 == svec row
    int m = mr >> 3;
    int slot = tid >> 7, e = tid & 127;
    const float* vec = (t < 32) ? &init_table[(size_t)(m * T_ + t) * D_]
                                : &s_vec[(size_t)m * D_];
    if (tid < 128) smem[tid] = vec[tid];
    __syncthreads();
    const float* w = &W1[((size_t)mr * 256 + slot * 128) * D_];
    float acc = 0.f;
#pragma unroll 8
    for (int c = 0; c < 128; ++c) acc = fmaf(smem[c], w[c * D_ + e], acc);
    if (slot == 0 && t < 32) acc += b1[mr * D_ + e];   // fold b1 into slot-a rows
    G[((size_t)(mr * 2 + slot) * 33 + t) * D_ + e] = acc;
  } else if (job < 1363) {               // -------- eaprep: eval-init tables --------
    int q = job - 1329;
    int m = q / 17, t = (q % 17) * 2 + (tid >> 7);
    int e = tid & 127;
    if (t <= 32) {
      const float* vec = (t < 32) ? &init_table[(size_t)(m * T_ + t) * D_]
                                  : &s_vec[(size_t)m * D_];
      const float* w = &We1[(size_t)m * D_ * D_];
      float acc = 0.f;
#pragma unroll 8
      for (int d = 0; d < 128; ++d) acc = fmaf(vec[d], w[d * D_ + e], acc);
      if (t < 32) {
        EA2[m * 4096 + ((e >> 1) * 32 + t) * 2 + (e & 1)] = acc + be1[m * D_ + e];
      } else {
        EWB[(m * D_ + e) * 2 + 0] = acc;
        EWB[(m * D_ + e) * 2 + 1] = we2[m * D_ + e];
      }
    }
  } else if (job == 1363) {              // -------- classify + lists --------
    for (int i = tid; i < 256; i += 256) fbm[i] = 0u;
    for (int i = tid; i < 40; i += 256) scnt[i] = 0;
    __syncthreads();
    for (int g = tid; g < ND_; g += 256) {
      if (par[2 * g] < NI_ && par[2 * g + 1] < NI_)
        atomicOr(&fbm[g >> 5], 1u << (g & 31));
    }
    __syncthreads();
    for (int g = tid; g < ND_; g += 256) {
      int r = ridx[g];
      int f = (fbm[g >> 5] >> (g & 31)) & 1;
      if (f) atomicAdd(&scnt[r], 1);
      else {
        int p0 = par[2 * g], p1 = par[2 * g + 1];
        int a0 = p0 < NI_ || ((fbm[(p0 - NI_) >> 5] >> ((p0 - NI_) & 31)) & 1);
        int a1 = p1 < NI_ || ((fbm[(p1 - NI_) >> 5] >> ((p1 - NI_) & 31)) & 1);
        if (a0 && a1) atomicAdd(&scnt[8 + r], 1);
        else atomicAdd(&scnt[16 + ((g >> 11) - 1) * 8 + r], 1);
      }
    }
    __syncthreads();
    if (tid == 0) {
      int run = 0;
      for (int r = 0; r < 8; ++r) { soff[r] = run; fsg[r] = run; cfg[r] = scnt[r]; run += scnt[r]; }
      run = 0;
      for (int r = 0; r < 8; ++r) { soff[8 + r] = run; fsgA[r] = run; cfgA[r] = scnt[8 + r]; run += scnt[8 + r]; }
      run = 0;
      for (int b = 0; b < 24; ++b) { soff[16 + b] = run; oB24[b] = run; cB24[b] = scnt[16 + b]; run += scnt[16 + b]; }
    }
    __syncthreads();
    for (int g = tid; g < ND_; g += 256) {
      int r = ridx[g];
      int f = (fbm[g >> 5] >> (g & 31)) & 1;
      if (f) fastlist[atomicAdd(&soff[r], 1)] = g;
      else {
        int p0 = par[2 * g], p1 = par[2 * g + 1];
        int a0 = p0 < NI_ || ((fbm[(p0 - NI_) >> 5] >> ((p0 - NI_) & 31)) & 1);
        int a1 = p1 < NI_ || ((fbm[(p1 - NI_) >> 5] >> ((p1 - NI_) & 31)) & 1);
        if (a0 && a1) slowAlist[atomicAdd(&soff[8 + r], 1)] = g;
        else slowBlist[atomicAdd(&soff[16 + ((g >> 11) - 1) * 8 + r], 1)] = g;
      }
    }
  } else {                               // -------- zero partial arrays (51200 B) --------
    for (int i = tid; i < 12800; i += 256) pzero[i] = 0u;
  }
}

// ================= main: fast rows (+fused eval) + eval-init + deriv pos/neg ====
// grid 2306. bid<1280: fast tile. bid<2304: eval-init. bid>=2304: deriv pos/neg sum.
__global__ __launch_bounds__(256) void main_kernel(
    const int* thax, const float* sine, const int* par,
    const float* pos, const float* neg,
    const float* b2, const float* tweaks,
    const float* G, const unsigned short* W2T, const unsigned short* We1T,
    const float* EA2, const float* EWB,
    const float* be1, const float* we2, const float* be2,
    const int* fsg, const int* cfg, const int* fastlist,
    unsigned short* sd,
    float* pA, float* pB, float* pPok, float* pNok, float* pTp, float* pTn) {
  __shared__ float sbuf[4448];
  int bid = blockIdx.x;
  int tid = threadIdx.x;
  int w = tid >> 6, lane = tid & 63;

  if (bid < 1280) {                       // ---------- fast rows ----------
    int m = bid / 640, q = bid % 640;
    int r = q / 80, tile = q % 80;
    int cnt = cfg[r];
    int base = tile * 16;
    if (base >= cnt) return;
    unsigned short* h_lds = (unsigned short*)sbuf;       // [16][128] bf16
    int*   t0a  = (int*)(sbuf + 1024);
    int*   t1a  = t0a + 16;
    float* s0a  = (float*)(t1a + 16);
    float* s1a  = s0a + 16;
    int*   gida = (int*)(s1a + 16);
    float* red2 = sbuf + 1104;                           // [4][16]
    if (tid < 16) {
      int loc = base + tid; if (loc >= cnt) loc = cnt - 1;
      int gid = fastlist[fsg[r] + loc];
      int p0 = par[2 * gid], p1 = par[2 * gid + 1];
      t0a[tid] = thax[p0]; s0a[tid] = sine[p0];
      t1a[tid] = thax[p1]; s1a[tid] = sine[p1];
      gida[tid] = gid;
    }
    __syncthreads();
    const float* Gm = &G[(size_t)(m * R_ + r) * 8448];
    {                                     // coop-build h (1 thread = row x 8 dims)
      int row = tid >> 4, seg = tid & 15, d0 = seg * 8;
      int t0 = t0a[row], t1 = t1a[row];
      float s0 = s0a[row], s1 = s1a[row];
      const float* pa = &Gm[t0 * 128 + d0];
      const float* pb = &Gm[(33 + t1) * 128 + d0];
      const float* pu = &Gm[4096 + d0];
      const float* pv = &Gm[8320 + d0];
      bf16x8 hv;
#pragma unroll
      for (int half = 0; half < 2; ++half) {
        float4 a = *(const float4*)(pa + half * 4);
        float4 b = *(const float4*)(pb + half * 4);
        float4 u = *(const float4*)(pu + half * 4);
        float4 v = *(const float4*)(pv + half * 4);
        hv[half * 4 + 0] = (__bf16)fmaxf(a.x + b.x + s0 * u.x + s1 * v.x, 0.f);
        hv[half * 4 + 1] = (__bf16)fmaxf(a.y + b.y + s0 * u.y + s1 * v.y, 0.f);
        hv[half * 4 + 2] = (__bf16)fmaxf(a.z + b.z + s0 * u.z + s1 * v.z, 0.f);
        hv[half * 4 + 3] = (__bf16)fmaxf(a.w + b.w + s0 * u.w + s1 * v.w, 0.f);
      }
      *(bf16x8*)&h_lds[row * 128 + (d0 ^ ((row & 7) << 3))] = hv;
    }
    __syncthreads();
    int l15 = lane & 15, l4 = lane >> 4;  // GEMM2: 4 waves x 2 f each
    const unsigned short* w2b = &W2T[(size_t)(m * R_ + r) * D_ * D_];
    f32x4 acc[2];
    acc[0] = (f32x4){0.f, 0.f, 0.f, 0.f};
    acc[1] = (f32x4){0.f, 0.f, 0.f, 0.f};
#pragma unroll
    for (int kc = 0; kc < 4; ++kc) {
      int d0 = kc * 32 + l4 * 8;
      bf16x8 a2 = ldb8(&h_lds[l15 * 128 + (d0 ^ ((l15 & 7) << 3))]);
#pragma unroll
      for (int f = 0; f < 2; ++f) {
        int fg = w * 2 + f;
        bf16x8 b = ldb8(&w2b[(fg * 16 + l15) * D_ + d0]);
        acc[f] = __builtin_amdgcn_mfma_f32_16x16x32_bf16(a2, b, acc[f], 0, 0, 0);
      }
    }
    float tw1 = tweaks[m * 2 + 1];
    const float* b2v = &b2[(m * R_ + r) * D_];
    __syncthreads();                      // done reading h_lds (GEMM2)
#pragma unroll
    for (int i = 0; i < 4; ++i) {
      int row = l4 * 4 + i;
      int g = base + row;
#pragma unroll
      for (int f = 0; f < 2; ++f) {
        int e = (w * 2 + f) * 16 + l15;
        unsigned short val = f2bu(acc[f][i] + b2v[e] + tw1);
        h_lds[row * 128 + (e ^ ((row & 7) << 3))] = val;
        if (g < cnt) sd[(size_t)(m * ND_ + gida[row]) * D_ + e] = val;
      }
    }
    __syncthreads();
    // fused eval: out @ We1 -> relu -> we2
    f32x4 ae[2];
    ae[0] = (f32x4){0.f, 0.f, 0.f, 0.f};
    ae[1] = (f32x4){0.f, 0.f, 0.f, 0.f};
    const unsigned short* we1b = &We1T[(size_t)m * D_ * D_];
#pragma unroll
    for (int kc = 0; kc < 4; ++kc) {
      int d0 = kc * 32 + l4 * 8;
      bf16x8 a2 = ldb8(&h_lds[l15 * 128 + (d0 ^ ((l15 & 7) << 3))]);
#pragma unroll
      for (int f = 0; f < 2; ++f) {
        int fg = w * 2 + f;
        bf16x8 b = ldb8(&we1b[(fg * 16 + l15) * D_ + d0]);
        ae[f] = __builtin_amdgcn_mfma_f32_16x16x32_bf16(a2, b, ae[f], 0, 0, 0);
      }
    }
    float part[4] = {0.f, 0.f, 0.f, 0.f};
#pragma unroll
    for (int f = 0; f < 2; ++f) {
      int e = (w * 2 + f) * 16 + l15;
      float bb = be1[m * D_ + e];
      float wv = we2[m * D_ + e];
#pragma unroll
      for (int i = 0; i < 4; ++i) {
        float he = ae[f][i] + bb;
        he = he > 0.f ? he : 0.f;
        part[i] += he * wv;
      }
    }
#pragma unroll
    for (int mask = 1; mask < 16; mask <<= 1) {
#pragma unroll
      for (int i = 0; i < 4; ++i) part[i] += __shfl_xor(part[i], mask, 64);
    }
    if (l15 == 0) {
#pragma unroll
      for (int i = 0; i < 4; ++i) red2[w * 16 + l4 * 4 + i] = part[i];
    }
    __syncthreads();
    if (tid < 16) {
      int g = base + tid;
      float v6[4] = {0.f, 0.f, 0.f, 0.f};
      if (g < cnt) {
        float logit = red2[tid] + red2[16 + tid] + red2[32 + tid] + red2[48 + tid]
                    + be2[m] + tweaks[m * 2 + 0];
        int grow = NI_ + gida[tid];
        float p_ = pos[grow], n_ = neg[grow];
        float lse = log1pf(__expf(-fabsf(logit)));
        v6[0] = p_ * (fmaxf(-logit, 0.f) + lse);
        v6[1] = n_ * (fmaxf(logit, 0.f) + lse);
        v6[2] = logit >= 0.f ? p_ : 0.f;
        v6[3] = logit < 0.f ? n_ : 0.f;
      }
#pragma unroll
      for (int mask = 1; mask < 16; mask <<= 1) {
#pragma unroll
        for (int qq = 0; qq < 4; ++qq) v6[qq] += __shfl_xor(v6[qq], mask, 64);
      }
      if (tid == 0) {
        int slot = 512 + r * 80 + tile;
        pA[m * PSTRIDE_ + slot] = v6[0];
        pB[m * PSTRIDE_ + slot] = v6[1];
        pPok[m * PSTRIDE_ + slot] = v6[2];
        pNok[m * PSTRIDE_ + slot] = v6[3];
      }
    }
  } else if (bid < 2304) {                // ---------- eval-init ----------
    int q = bid - 1280;
    int m = q >> 9, xb = q & 511;
    float* lea = sbuf;                    // [p=64][t=32][2]
    float* lwb = sbuf + 4096;             // [e=128][{EB,we2}]
    float* red = sbuf + 4352;
    for (int i = tid; i < 4096; i += 256) lea[i] = EA2[m * 4096 + i];
    if (tid < 256) lwb[tid] = EWB[m * 256 + tid];
    __syncthreads();
    int row = xb * 256 + tid;
    int t = thax[row];
    float s = sine[row];
    float acc = 0.f;
#pragma unroll 8
    for (int p = 0; p < 64; ++p) {
      float2 ea = *(const float2*)&lea[(p * 32 + t) * 2];
      float4 wb = *(const float4*)&lwb[p * 4];
      float x0 = fmaf(s, wb.x, ea.x); x0 = fmaxf(x0, 0.f);
      acc = fmaf(x0, wb.y, acc);
      float x1 = fmaf(s, wb.z, ea.y); x1 = fmaxf(x1, 0.f);
      acc = fmaf(x1, wb.w, acc);
    }
    float logit = acc + be2[m] + tweaks[m * 2 + 0];
    float p_ = pos[row], n_ = neg[row];
    float lse = log1pf(__expf(-fabsf(logit)));
    float v[6];
    v[0] = p_ * (fmaxf(-logit, 0.f) + lse);
    v[1] = n_ * (fmaxf(logit, 0.f) + lse);
    v[2] = logit >= 0.f ? p_ : 0.f;
    v[3] = logit < 0.f ? n_ : 0.f;
    v[4] = p_; v[5] = n_;
#pragma unroll
    for (int mask = 1; mask < 64; mask <<= 1) {
#pragma unroll
      for (int k = 0; k < 6; ++k) v[k] += __shfl_xor(v[k], mask, 64);
    }
    if (lane == 0) {
#pragma unroll
      for (int k = 0; k < 6; ++k) red[k * 16 + w] = v[k];
    }
    __syncthreads();
    if (tid == 0) {
      float t6[6];
#pragma unroll
      for (int k = 0; k < 6; ++k)
        t6[k] = red[k * 16 + 0] + red[k * 16 + 1] + red[k * 16 + 2] + red[k * 16 + 3];
      pA[m * PSTRIDE_ + xb] = t6[0];
      pB[m * PSTRIDE_ + xb] = t6[1];
      pPok[m * PSTRIDE_ + xb] = t6[2];
      pNok[m * PSTRIDE_ + xb] = t6[3];
      if (m == 0) { pTp[xb] = t6[4]; pTn[xb] = t6[5]; }
    }
  } else {                                // ---------- deriv pos/neg total ----------
    int j = bid - 2304;                   // 0: pos, 1: neg
    float* red = sbuf;
    const float* src = j ? neg : pos;
    float s = 0.f;
    for (int i = NI_ + tid; i < N_; i += 256) s += src[i];
#pragma unroll
    for (int mask = 1; mask < 64; mask <<= 1) s += __shfl_xor(s, mask, 64);
    if (lane == 0) red[w] = s;
    __syncthreads();
    if (tid == 0) {
      float t = red[0] + red[1] + red[2] + red[3];
      if (j == 0) pTp[1152] = t; else pTn[1152] = t;
    }
  }
}

// ================= slowA: all-layer slow rows with fast/init parents ===========
// grid (6, 8, 2), 128 threads (2 waves, f-split 4+4). Parents ready after main.
__global__ __launch_bounds__(128) void slowA_kernel(
    const int* thax, const float* sine, const int* par,
    const float* b1, const float* b2, const float* tweaks,
    const float* pos, const float* neg,
    const float* be1, const float* we2, const float* be2,
    const unsigned short* tab, const unsigned short* svec,
    const unsigned short* W1T, const unsigned short* W2T,
    const unsigned short* We1T,
    const int* fsgA, const int* cfgA, const int* slowAlist,
    unsigned short* sd,
    float* pA, float* pB, float* pPok, float* pNok) {
  int tile = blockIdx.x, r = blockIdx.y, m = blockIdx.z;
  int cnt = cfgA[r];
  int base = tile * 16;
  if (base >= cnt) return;
  int start = fsgA[r];
  int tid = threadIdx.x;
  int w = tid >> 6, lane = tid & 63;
  int l15 = lane & 15, l4 = lane >> 4;
  __shared__ unsigned short h_lds[16 * 128];
  __shared__ float red2[32];
  __shared__ int grows[16];

  if (tid < 16) {
    int loc = base + tid; if (loc >= cnt) loc = cnt - 1;
    grows[tid] = slowAlist[start + loc];
  }
  __syncthreads();
  int g0 = grows[l15];
  int p0 = par[2 * g0], p1 = par[2 * g0 + 1];
  const unsigned short* w1b = &W1T[(size_t)(m * R_ + r) * D_ * 256];
  const unsigned short* w2b = &W2T[(size_t)(m * R_ + r) * D_ * D_];
  const unsigned short* we1b = &We1T[(size_t)m * D_ * D_];

  bf16x8 av[8];
#pragma unroll
  for (int kc = 0; kc < 8; ++kc) {
    int k = kc * 32 + l4 * 8;
    int p = (k < 128) ? p0 : p1;
    av[kc] = node_chunk(m, p, k & 127, tab, svec, sd, thax, sine);
  }
  f32x4 acch[4];
#pragma unroll
  for (int f = 0; f < 4; ++f) acch[f] = (f32x4){0.f, 0.f, 0.f, 0.f};
#pragma unroll
  for (int kc = 0; kc < 8; ++kc) {
    int k = kc * 32 + l4 * 8;
#pragma unroll
    for (int f = 0; f < 4; ++f) {
      int fg = w * 4 + f;
      bf16x8 b = ldb8(&w1b[(fg * 16 + l15) * 256 + k]);
      acch[f] = __builtin_amdgcn_mfma_f32_16x16x32_bf16(av[kc], b, acch[f], 0, 0, 0);
    }
  }
  const float* b1v = &b1[(m * R_ + r) * D_];
#pragma unroll
  for (int f = 0; f < 4; ++f) {
    int d = (w * 4 + f) * 16 + l15;
    float bb = b1v[d];
#pragma unroll
    for (int i = 0; i < 4; ++i) {
      int row = l4 * 4 + i;
      float h = acch[f][i] + bb;
      h = h > 0.f ? h : 0.f;
      h_lds[row * 128 + (d ^ ((row & 7) << 3))] = f2bu(h);
    }
  }
  __syncthreads();
  f32x4 acco[4];
#pragma unroll
  for (int f = 0; f < 4; ++f) acco[f] = (f32x4){0.f, 0.f, 0.f, 0.f};
#pragma unroll
  for (int kc = 0; kc < 4; ++kc) {
    int d0 = kc * 32 + l4 * 8;
    bf16x8 a2 = ldb8(&h_lds[l15 * 128 + (d0 ^ ((l15 & 7) << 3))]);
#pragma unroll
    for (int f = 0; f < 4; ++f) {
      int fg = w * 4 + f;
      bf16x8 b = ldb8(&w2b[(fg * 16 + l15) * D_ + d0]);
      acco[f] = __builtin_amdgcn_mfma_f32_16x16x32_bf16(a2, b, acco[f], 0, 0, 0);
    }
  }
  float tw1 = tweaks[m * 2 + 1];
  const float* b2v = &b2[(m * R_ + r) * D_];
  __syncthreads();
#pragma unroll
  for (int i = 0; i < 4; ++i) {
    int row = l4 * 4 + i;
    int g = base + row;
#pragma unroll
    for (int f = 0; f < 4; ++f) {
      int e = (w * 4 + f) * 16 + l15;
      unsigned short val = f2bu(acco[f][i] + b2v[e] + tw1);
      h_lds[row * 128 + (e ^ ((row & 7) << 3))] = val;
      if (g < cnt) sd[(size_t)(m * ND_ + grows[row]) * D_ + e] = val;
    }
  }
  __syncthreads();
  f32x4 ae[4];
#pragma unroll
  for (int f = 0; f < 4; ++f) ae[f] = (f32x4){0.f, 0.f, 0.f, 0.f};
#pragma unroll
  for (int kc = 0; kc < 4; ++kc) {
    int d0 = kc * 32 + l4 * 8;
    bf16x8 a2 = ldb8(&h_lds[l15 * 128 + (d0 ^ ((l15 & 7) << 3))]);
#pragma unroll
    for (int f = 0; f < 4; ++f) {
      int fg = w * 4 + f;
      bf16x8 b = ldb8(&we1b[(fg * 16 + l15) * D_ + d0]);
      ae[f] = __builtin_amdgcn_mfma_f32_16x16x32_bf16(a2, b, ae[f], 0, 0, 0);
    }
  }
  float part[4] = {0.f, 0.f, 0.f, 0.f};
#pragma unroll
  for (int f = 0; f < 4; ++f) {
    int e = (w * 4 + f) * 16 + l15;
    float bb = be1[m * D_ + e];
    float wv = we2[m * D_ + e];
#pragma unroll
    for (int i = 0; i < 4; ++i) {
      float he = ae[f][i] + bb;
      he = he > 0.f ? he : 0.f;
      part[i] += he * wv;
    }
  }
#pragma unroll
  for (int mask = 1; mask < 16; mask <<= 1) {
#pragma unroll
    for (int i = 0; i < 4; ++i) part[i] += __shfl_xor(part[i], mask, 64);
  }
  if (l15 == 0) {
#pragma unroll
    for (int i = 0; i < 4; ++i) red2[w * 16 + l4 * 4 + i] = part[i];
  }
  __syncthreads();
  if (tid < 16) {
    int g = base + tid;
    float v6[4] = {0.f, 0.f, 0.f, 0.f};
    if (g < cnt) {
      float logit = red2[tid] + red2[16 + tid] + be2[m] + tweaks[m * 2 + 0];
      int grow = NI_ + grows[tid];
      float p_ = pos[grow], n_ = neg[grow];
      float lse = log1pf(__expf(-fabsf(logit)));
      v6[0] = p_ * (fmaxf(-logit, 0.f) + lse);
      v6[1] = n_ * (fmaxf(logit, 0.f) + lse);
      v6[2] = logit >= 0.f ? p_ : 0.f;
      v6[3] = logit < 0.f ? n_ : 0.f;
    }
#pragma unroll
    for (int mask = 1; mask < 16; mask <<= 1) {
#pragma unroll
      for (int qq = 0; qq < 4; ++qq) v6[qq] += __shfl_xor(v6[qq], mask, 64);
    }
    if (tid == 0) {
      int slot = 1153 + r * 6 + tile;
      pA[m * PSTRIDE_ + slot] = v6[0];
      pB[m * PSTRIDE_ + slot] = v6[1];
      pPok[m * PSTRIDE_ + slot] = v6[2];
      pNok[m * PSTRIDE_ + slot] = v6[3];
    }
  }
}

// ================= slowB layer l: chained slow rows (+fused eval), spin-free ====
// grid (2, 8, 2), 128 threads. Parents ready after slowA / previous slowB launch.
__global__ __launch_bounds__(128) void slowB_kernel(int l,
    const int* thax, const float* sine, const int* par,
    const float* b1, const float* b2, const float* tweaks,
    const float* pos, const float* neg,
    const float* be1, const float* we2, const float* be2,
    const unsigned short* tab, const unsigned short* svec,
    const unsigned short* W1T, const unsigned short* W2T,
    const unsigned short* We1T,
    const int* cB24, const int* oB24, const int* slowBlist,
    unsigned short* sd,
    float* pA, float* pB, float* pPok, float* pNok) {
  int tile = blockIdx.x, r = blockIdx.y, m = blockIdx.z;
  int bkt = (l - 1) * 8 + r;
  int cnt = cB24[bkt];
  int base = tile * 16;
  if (base >= cnt) return;
  int off = oB24[bkt];
  int tid = threadIdx.x;
  int w = tid >> 6, lane = tid & 63;
  int l15 = lane & 15, l4 = lane >> 4;
  __shared__ unsigned short h_lds[16 * 128];
  __shared__ float red2[32];
  __shared__ int grows[16];

  if (tid < 16) {
    int loc = base + tid; if (loc >= cnt) loc = cnt - 1;
    grows[tid] = slowBlist[off + loc];
  }
  __syncthreads();
  int g0 = grows[l15];
  int p0 = par[2 * g0], p1 = par[2 * g0 + 1];
  const unsigned short* w1b = &W1T[(size_t)(m * R_ + r) * D_ * 256];
  const unsigned short* w2b = &W2T[(size_t)(m * R_ + r) * D_ * D_];
  const unsigned short* we1b = &We1T[(size_t)m * D_ * D_];

  bf16x8 av[8];
#pragma unroll
  for (int kc = 0; kc < 8; ++kc) {
    int k = kc * 32 + l4 * 8;
    int p = (k < 128) ? p0 : p1;
    av[kc] = node_chunk(m, p, k & 127, tab, svec, sd, thax, sine);
  }
  f32x4 acch[4];
#pragma unroll
  for (int f = 0; f < 4; ++f) acch[f] = (f32x4){0.f, 0.f, 0.f, 0.f};
#pragma unroll
  for (int kc = 0; kc < 8; ++kc) {
    int k = kc * 32 + l4 * 8;
#pragma unroll
    for (int f = 0; f < 4; ++f) {
      int fg = w * 4 + f;
      bf16x8 b = ldb8(&w1b[(fg * 16 + l15) * 256 + k]);
      acch[f] = __builtin_amdgcn_mfma_f32_16x16x32_bf16(av[kc], b, acch[f], 0, 0, 0);
    }
  }
  const float* b1v = &b1[(m * R_ + r) * D_];
#pragma unroll
  for (int f = 0; f < 4; ++f) {
    int d = (w * 4 + f) * 16 + l15;
    float bb = b1v[d];
#pragma unroll
    for (int i = 0; i < 4; ++i) {
      int row = l4 * 4 + i;
      float h = acch[f][i] + bb;
      h = h > 0.f ? h : 0.f;
      h_lds[row * 128 + (d ^ ((row & 7) << 3))] = f2bu(h);
    }
  }
  __syncthreads();
  f32x4 acco[4];
#pragma unroll
  for (int f = 0; f < 4; ++f) acco[f] = (f32x4){0.f, 0.f, 0.f, 0.f};
#pragma unroll
  for (int kc = 0; kc < 4; ++kc) {
    int d0 = kc * 32 + l4 * 8;
    bf16x8 a2 = ldb8(&h_lds[l15 * 128 + (d0 ^ ((l15 & 7) << 3))]);
#pragma unroll
    for (int f = 0; f < 4; ++f) {
      int fg = w * 4 + f;
      bf16x8 b = ldb8(&w2b[(fg * 16 + l15) * D_ + d0]);
      acco[f] = __builtin_amdgcn_mfma_f32_16x16x32_bf16(a2, b, acco[f], 0, 0, 0);
    }
  }
  float tw1 = tweaks[m * 2 + 1];
  const float* b2v = &b2[(m * R_ + r) * D_];
  __syncthreads();
#pragma unroll
  for (int i = 0; i < 4; ++i) {
    int row = l4 * 4 + i;
    int g = base + row;
#pragma unroll
    for (int f = 0; f < 4; ++f) {
      int e = (w * 4 + f) * 16 + l15;
      unsigned short val = f2bu(acco[f][i] + b2v[e] + tw1);
      h_lds[row * 128 + (e ^ ((row & 7) << 3))] = val;
      if (g < cnt) sd[(size_t)(m * ND_ + grows[row]) * D_ + e] = val;
    }
  }
  __syncthreads();
  f32x4 ae[4];
#pragma unroll
  for (int f = 0; f < 4; ++f) ae[f] = (f32x4){0.f, 0.f, 0.f, 0.f};
#pragma unroll
  for (int kc = 0; kc < 4; ++kc) {
    int d0 = kc * 32 + l4 * 8;
    bf16x8 a2 = ldb8(&h_lds[l15 * 128 + (d0 ^ ((l15 & 7) << 3))]);
#pragma unroll
    for (int f = 0; f < 4; ++f) {
      int fg = w * 4 + f;
      bf16x8 b = ldb8(&we1b[(fg * 16 + l15) * D_ + d0]);
      ae[f] = __builtin_amdgcn_mfma_f32_16x16x32_bf16(a2, b, ae[f], 0, 0, 0);
    }
  }
  float part[4] = {0.f, 0.f, 0.f, 0.f};
#pragma unroll
  for (int f = 0; f < 4; ++f) {
    int e = (w * 4 + f) * 16 + l15;
    float bb = be1[m * D_ + e];
    float wv = we2[m * D_ + e];
#pragma unroll
    for (int i = 0; i < 4; ++i) {
      float he = ae[f][i] + bb;
      he = he > 0.f ? he : 0.f;
      part[i] += he * wv;
    }
  }
#pragma unroll
  for (int mask = 1; mask < 16; mask <<= 1) {
#pragma unroll
    for (int i = 0; i < 4; ++i) part[i] += __shfl_xor(part[i], mask, 64);
  }
  if (l15 == 0) {
#pragma unroll
    for (int i = 0; i < 4; ++i) red2[w * 16 + l4 * 4 + i] = part[i];
  }
  __syncthreads();
  if (tid < 16) {
    int g = base + tid;
    float v6[4] = {0.f, 0.f, 0.f, 0.f};
    if (g < cnt) {
      float logit = red2[tid] + red2[16 + tid] + be2[m] + tweaks[m * 2 + 0];
      int grow = NI_ + grows[tid];
      float p_ = pos[grow], n_ = neg[grow];
      float lse = log1pf(__expf(-fabsf(logit)));
      v6[0] = p_ * (fmaxf(-logit, 0.f) + lse);
      v6[1] = n_ * (fmaxf(logit, 0.f) + lse);
      v6[2] = logit >= 0.f ? p_ : 0.f;
      v6[3] = logit < 0.f ? n_ : 0.f;
    }
#pragma unroll
    for (int mask = 1; mask < 16; mask <<= 1) {
#pragma unroll
      for (int qq = 0; qq < 4; ++qq) v6[qq] += __shfl_xor(v6[qq], mask, 64);
    }
    if (tid == 0) {
      int slot = 1201 + (l - 2) * 16 + r * 2 + tile;
      pA[m * PSTRIDE_ + slot] = v6[0];
      pB[m * PSTRIDE_ + slot] = v6[1];
      pPok[m * PSTRIDE_ + slot] = v6[2];
      pNok[m * PSTRIDE_ + slot] = v6[3];
    }
  }
}

// ---------------- deterministic final reduction ----------------
__global__ __launch_bounds__(256) void finalize_kernel(
    const float* pA, const float* pB, const float* pPok, const float* pNok,
    const float* pTp, const float* pTn, float* out) {
  __shared__ float lred[10][4];
  const float* srcs[10] = {pA, pA + PSTRIDE_, pB, pB + PSTRIDE_,
                           pPok, pPok + PSTRIDE_, pNok, pNok + PSTRIDE_,
                           pTp, pTn};
  int tid = threadIdx.x;
  int w = tid >> 6, lane = tid & 63;
#pragma unroll
  for (int q = 0; q < 10; ++q) {
    float s = 0.f;
    for (int i = tid; i < PUSED_; i += 256) s += srcs[q][i];
#pragma unroll
    for (int mask = 1; mask < 64; mask <<= 1) s += __shfl_xor(s, mask, 64);
    if (lane == 0) lred[q][w] = s;
  }
  __syncthreads();
  if (tid == 0) {
    float totals[10];
#pragma unroll
    for (int q = 0; q < 10; ++q)
      totals[q] = lred[q][0] + lred[q][1] + lred[q][2] + lred[q][3];
    float tp = totals[8], tn = totals[9];
    float pw = tn / tp;
    out[0] = pw * totals[0] + totals[2];
    out[1] = pw * totals[1] + totals[3];
    out[2] = totals[4]; out[3] = totals[5];
    out[4] = totals[6]; out[5] = totals[7];
    out[6] = tp; out[7] = tn;
  }
}

extern "C" void kernel_launch(void* const* d_in, const int* in_sizes, int n_in,
                              void* d_out, int out_size, void* d_ws, size_t ws_size,
                              hipStream_t stream) {
  const int*   thax = (const int*)d_in[0];
  const float* sine = (const float*)d_in[1];
  const int*   par  = (const int*)d_in[2];
  const int*   ridx = (const int*)d_in[3];
  const float* pos  = (const float*)d_in[4];
  const float* neg  = (const float*)d_in[5];
  const float* init_table = (const float*)d_in[6];
  const float* s_vec = (const float*)d_in[7];
  const float* W1 = (const float*)d_in[8];
  const float* b1 = (const float*)d_in[9];
  const float* W2 = (const float*)d_in[10];
  const float* b2 = (const float*)d_in[11];
  const float* tweaks = (const float*)d_in[12];
  const float* We1 = (const float*)d_in[13];
  const float* be1 = (const float*)d_in[14];
  const float* we2 = (const float*)d_in[15];
  const float* be2 = (const float*)d_in[16];

  char* ws = (char*)d_ws;
  unsigned short* W1T  = (unsigned short*)(ws + OFF_W1T);
  unsigned short* W2T  = (unsigned short*)(ws + OFF_W2T);
  unsigned short* We1T = (unsigned short*)(ws + OFF_WE1T);
  unsigned short* tab  = (unsigned short*)(ws + OFF_TAB);
  unsigned short* svec = (unsigned short*)(ws + OFF_SVEC);
  float* EA2  = (float*)(ws + OFF_EA2);
  float* EWB  = (float*)(ws + OFF_EWB);
  float* pA   = (float*)(ws + OFF_PA);
  float* pB   = (float*)(ws + OFF_PB);
  float* pPok = (float*)(ws + OFF_PPOK);
  float* pNok = (float*)(ws + OFF_PNOK);
  float* pTp  = (float*)(ws + OFF_PTP);
  float* pTn  = (float*)(ws + OFF_PTN);
  float* G    = (float*)(ws + OFF_G);
  unsigned short* sd = (unsigned short*)(ws + OFF_STORE);
  int* fsg      = (int*)(ws + OFF_FSG);
  int* cfg      = (int*)(ws + OFF_CFG);
  int* fastlist = (int*)(ws + OFF_FLIST);
  int* slowAlist = (int*)(ws + OFF_SAL);
  int* slowBlist = (int*)(ws + OFF_SBL);
  int* fsgA     = (int*)(ws + OFF_FSGA);
  int* cfgA     = (int*)(ws + OFF_CFGA);
  int* cB24     = (int*)(ws + OFF_CB24);
  int* oB24     = (int*)(ws + OFF_OB24);

  megaprep_kernel<<<1365, 256, 0, stream>>>(
      W1, W2, We1, init_table, s_vec, b1, be1, we2, ridx, par,
      W1T, W2T, We1T, tab, svec, G, EA2, EWB,
      fsg, cfg, fastlist, fsgA, cfgA, slowAlist, cB24, oB24, slowBlist,
      (unsigned int*)pA);
  main_kernel<<<2306, 256, 0, stream>>>(
      thax, sine, par, pos, neg, b2, tweaks, G, W2T, We1T, EA2, EWB,
      be1, we2, be2, fsg, cfg, fastlist, sd,
      pA, pB, pPok, pNok, pTp, pTn);
  slowA_kernel<<<dim3(6, R_, M_), 128, 0, stream>>>(
      thax, sine, par, b1, b2, tweaks, pos, neg, be1, we2, be2,
      tab, svec, W1T, W2T, We1T, fsgA, cfgA, slowAlist, sd,
      pA, pB, pPok, pNok);
  for (int l = 2; l < L_; ++l) {          // layer-1 slow rows are all in slowA
    slowB_kernel<<<dim3(2, R_, M_), 128, 0, stream>>>(
        l, thax, sine, par, b1, b2, tweaks, pos, neg, be1, we2, be2,
        tab, svec, W1T, W2T, We1T, cB24, oB24, slowBlist, sd,
        pA, pB, pPok, pNok);
  }
  finalize_kernel<<<1, 256, 0, stream>>>(pA, pB, pPok, pNok, pTp, pTn,
                                         (float*)d_out);
}

// Round 15
// 95.764 us; speedup vs baseline: 3.8073x; 1.1327x over previous
//
#include <hip/hip_runtime.h>
#include <hip/hip_bf16.h>

#define M_ 2
#define D_ 128
#define NI_ 131072
#define L_ 4
#define NPL_ 2048
#define R_ 8
#define T_ 32
#define N_ (NI_ + L_ * NPL_)   // 139264
#define ND_ (L_ * NPL_)        // 8192 deriv nodes
#define PSTRIDE_ 1280          // per-model partial stride (floats)
#define PUSED_ 1248            // used slots: 512 init + 640 fast + 1 posneg + 48 slowA + 32 slowB
#define FCAP_ 1280             // fast rows capacity per rule   (exp ~979, +10 sigma)
#define ACAP_ 96               // slowA capacity per rule       (exp ~45)
#define BCAP_ 32               // slowB capacity per (l-1,rule) (exp ~1)

typedef __bf16 bf16x8 __attribute__((ext_vector_type(8)));
typedef float f32x4 __attribute__((ext_vector_type(4)));

// ---- ws layout (bytes) ----
#define OFF_W1T    0u            // [M][R][128(d)][256(c)] bf16 = 1048576
#define OFF_W2T    1048576u      // [M][R][128(e)][128(d)] bf16 = 524288
#define OFF_WE1T   1572864u      // [M][128(e)][128(d)] bf16    = 65536
#define OFF_TAB    1638400u      // [M][T][128] bf16            = 16384
#define OFF_SVEC   1654784u      // [M][128] bf16               = 512
#define OFF_EA2    1688448u      // [M][64][32][2] f32          = 32768
#define OFF_EWB    1721216u      // [M][128][2] f32             = 2048
#define OFF_PA     1723264u      // [2][1280] f32 = 10240
#define OFF_PB     1733504u
#define OFF_PPOK   1743744u
#define OFF_PNOK   1753984u
#define OFF_PTP    1764224u      // [1280] f32 = 5120
#define OFF_PTN    1769344u      // end 1774464 (zero span = 51200 B)
#define OFF_G      1774464u      // [M][R][2][33][128] f32 = 540672
#define OFF_STORE  2315136u      // [M][8192][128] bf16 = 4194304
#define OFF_FLIST  6509440u      // [8][1280] int = 40960 (fixed-cap fast buckets)
#define OFF_SAL    6550400u      // [8][96] int = 3072
#define OFF_SBL    6553472u      // [24][32] int = 3072
#define OFF_CFG    6556544u      // [8] int
#define OFF_CFGA   6556576u      // [8] int
#define OFF_CB24   6556608u      // [24] int ; end ~6.56MB

__device__ __forceinline__ unsigned short f2bu(float f) {
  unsigned int u = __float_as_uint(f);
  u += 0x7fffu + ((u >> 16) & 1u);        // RNE (finite values only)
  return (unsigned short)(u >> 16);
}
__device__ __forceinline__ bf16x8 ldb8(const unsigned short* p) {
  return *reinterpret_cast<const bf16x8*>(p);
}

// value of node `row` (global id), 8 dims from d0 (slow paths only).
__device__ __forceinline__ bf16x8 node_chunk(int m, int row, int d0,
    const unsigned short* tab, const unsigned short* svec,
    const unsigned short* sd, const int* thax, const float* sine) {
  if (row < NI_) {
    bf16x8 tv = ldb8(&tab[(m * T_ + thax[row]) * D_ + d0]);
    bf16x8 sv = ldb8(&svec[m * D_ + d0]);
    float sn = sine[row];
    bf16x8 r;
#pragma unroll
    for (int j = 0; j < 8; ++j)
      r[j] = (__bf16)((float)tv[j] + sn * (float)sv[j]);
    return r;
  }
  return ldb8(&sd[(size_t)(m * ND_ + (row - NI_)) * D_ + d0]);
}

// ================= mega-prep =================
// jobs (serial-tail-prone jobs FIRST so they overlap the wide phase):
//   [0,40)     classify bucket j: 8 fast rules, 8 slowA rules, 24 slowB (l-1,r)
//   40         zero partial arrays
//   41         tab/svec bf16 convert
//   [42,76)    eaprep (eval-init tables)
//   [76,604)   gprep (G tables)
//   [604,1404) transposes
__global__ __launch_bounds__(256) void megaprep_kernel(
    const float* W1, const float* W2, const float* We1,
    const float* init_table, const float* s_vec,
    const float* b1, const float* be1, const float* we2,
    const int* ridx, const int* par,
    unsigned short* W1T, unsigned short* W2T, unsigned short* We1T,
    unsigned short* tab, unsigned short* svec,
    float* G, float* EA2, float* EWB,
    int* fastlist, int* slowAlist, int* slowBlist,
    int* cfg, int* cfgA, int* cB24, unsigned int* pzero) {
  __shared__ float smem[1056];
  __shared__ int lcnt;
  int job = blockIdx.x;
  int tid = threadIdx.x;

  if (job < 40) {                        // -------- classify (ballot-compaction) ----
    int* out; int bucketbase, cap;
    if (job < 8)       { out = fastlist;  bucketbase = job * FCAP_;        cap = FCAP_; }
    else if (job < 16) { out = slowAlist; bucketbase = (job - 8) * ACAP_;  cap = ACAP_; }
    else               { out = slowBlist; bucketbase = (job - 16) * BCAP_; cap = BCAP_; }
    if (tid == 0) lcnt = 0;
    __syncthreads();
    int lane = tid & 63;
    unsigned long long lmask_lt = (1ull << lane) - 1ull;
    for (int g = tid; g < ND_; g += 256) {
      int p0 = par[2 * g], p1 = par[2 * g + 1];
      bool fast = (p0 < NI_) && (p1 < NI_);
      bool match;
      if (job < 8) {
        match = fast && (ridx[g] == job);
      } else if (fast) {
        match = false;
      } else {
        bool a0 = (p0 < NI_) ||
                  (par[2 * (p0 - NI_)] < NI_ && par[2 * (p0 - NI_) + 1] < NI_);
        bool a1 = (p1 < NI_) ||
                  (par[2 * (p1 - NI_)] < NI_ && par[2 * (p1 - NI_) + 1] < NI_);
        bool isA = a0 && a1;
        if (job < 16) match = isA && (ridx[g] == job - 8);
        else match = !isA && ((((g >> 11) - 1) * 8 + ridx[g]) == job - 16);
      }
      unsigned long long mask = __ballot(match);
      if (mask) {
        int leader = __ffsll((unsigned long long)mask) - 1;
        int pre = __popcll(mask & lmask_lt);
        int base_ = 0;
        if (lane == leader) base_ = atomicAdd(&lcnt, __popcll(mask));
        base_ = __shfl(base_, leader, 64);
        if (match) {
          int idx = base_ + pre;
          if (idx < cap) out[bucketbase + idx] = g;
        }
      }
    }
    __syncthreads();
    if (tid == 0) {
      int c = lcnt; if (c > cap) c = cap;
      if (job < 8) cfg[job] = c;
      else if (job < 16) cfgA[job - 8] = c;
      else cB24[job - 16] = c;
    }
  } else if (job == 40) {                // -------- zero partial arrays (51200 B) ----
    for (int i = tid; i < 12800; i += 256) pzero[i] = 0u;
  } else if (job == 41) {                // -------- tab/svec convert --------
    for (int i = tid; i < 8448; i += 256) {
      if (i < 8192) tab[i] = f2bu(init_table[i]);
      else svec[i - 8192] = f2bu(s_vec[i - 8192]);
    }
  } else if (job < 76) {                 // -------- eaprep: eval-init tables --------
    int q = job - 42;
    int m = q / 17, t = (q % 17) * 2 + (tid >> 7);
    int e = tid & 127;
    if (t <= 32) {
      const float* vec = (t < 32) ? &init_table[(size_t)(m * T_ + t) * D_]
                                  : &s_vec[(size_t)m * D_];
      const float* w = &We1[(size_t)m * D_ * D_];
      float acc = 0.f;
#pragma unroll 8
      for (int d = 0; d < 128; ++d) acc = fmaf(vec[d], w[d * D_ + e], acc);
      if (t < 32) {
        EA2[m * 4096 + ((e >> 1) * 32 + t) * 2 + (e & 1)] = acc + be1[m * D_ + e];
      } else {
        EWB[(m * D_ + e) * 2 + 0] = acc;
        EWB[(m * D_ + e) * 2 + 1] = we2[m * D_ + e];
      }
    }
  } else if (job < 604) {                // -------- gprep: G[m][r][slot][t][e] --------
    int q = job - 76;
    int t = q / 16, mr = q & 15;         // t in [0,32], 32 == svec row
    int m = mr >> 3;
    int slot = tid >> 7, e = tid & 127;
    const float* vec = (t < 32) ? &init_table[(size_t)(m * T_ + t) * D_]
                                : &s_vec[(size_t)m * D_];
    if (tid < 128) smem[tid] = vec[tid];
    __syncthreads();
    const float* w = &W1[((size_t)mr * 256 + slot * 128) * D_];
    float acc = 0.f;
#pragma unroll 8
    for (int c = 0; c < 128; ++c) acc = fmaf(smem[c], w[c * D_ + e], acc);
    if (slot == 0 && t < 32) acc += b1[mr * D_ + e];   // fold b1 into slot-a rows
    G[((size_t)(mr * 2 + slot) * 33 + t) * D_ + e] = acc;
  } else {                               // -------- transposes --------
    int q0 = job - 604;
    int z, rblk, cblk;
    if (q0 < 512)      { z = q0 >> 5;            rblk = (q0 & 31) >> 2; cblk = q0 & 3; }
    else if (q0 < 768) { int q = q0 - 512; z = 16 + (q >> 4); rblk = (q & 15) >> 2; cblk = q & 3; }
    else               { int q = q0 - 768; z = 32 + (q >> 4); rblk = (q & 15) >> 2; cblk = q & 3; }
    const float* src; unsigned short* dst; int R;
    if (z < 16)      { src = W1  + (size_t)z * 32768;        dst = W1T  + (size_t)z * 32768;        R = 256; }
    else if (z < 32) { src = W2  + (size_t)(z - 16) * 16384; dst = W2T  + (size_t)(z - 16) * 16384; R = 128; }
    else             { src = We1 + (size_t)(z - 32) * 16384; dst = We1T + (size_t)(z - 32) * 16384; R = 128; }
    int r0 = rblk * 32, c0 = cblk * 32;
    float (*tile)[33] = (float(*)[33])smem;
    int tx = tid & 31, ty = tid >> 5;
#pragma unroll
    for (int k = 0; k < 4; ++k)
      tile[ty + 8 * k][tx] = src[(size_t)(r0 + ty + 8 * k) * D_ + c0 + tx];
    __syncthreads();
#pragma unroll
    for (int k = 0; k < 4; ++k)
      dst[(size_t)(c0 + ty + 8 * k) * R + r0 + tx] = f2bu(tile[tx][ty + 8 * k]);
  }
}

// ================= main: fast rows (+fused eval) + eval-init + deriv pos/neg ====
// grid 2306. bid<1280: fast tile. bid<2304: eval-init. bid>=2304: deriv pos/neg sum.
__global__ __launch_bounds__(256) void main_kernel(
    const int* thax, const float* sine, const int* par,
    const float* pos, const float* neg,
    const float* b2, const float* tweaks,
    const float* G, const unsigned short* W2T, const unsigned short* We1T,
    const float* EA2, const float* EWB,
    const float* be1, const float* we2, const float* be2,
    const int* cfg, const int* fastlist,
    unsigned short* sd,
    float* pA, float* pB, float* pPok, float* pNok, float* pTp, float* pTn) {
  __shared__ float sbuf[4448];
  int bid = blockIdx.x;
  int tid = threadIdx.x;
  int w = tid >> 6, lane = tid & 63;

  if (bid < 1280) {                       // ---------- fast rows ----------
    int m = bid / 640, q = bid % 640;
    int r = q / 80, tile = q % 80;
    int cnt = cfg[r];
    int base = tile * 16;
    if (base >= cnt) return;
    unsigned short* h_lds = (unsigned short*)sbuf;       // [16][128] bf16
    int*   t0a  = (int*)(sbuf + 1024);
    int*   t1a  = t0a + 16;
    float* s0a  = (float*)(t1a + 16);
    float* s1a  = s0a + 16;
    int*   gida = (int*)(s1a + 16);
    float* red2 = sbuf + 1104;                           // [4][16]
    if (tid < 16) {
      int loc = base + tid; if (loc >= cnt) loc = cnt - 1;
      int gid = fastlist[r * FCAP_ + loc];
      int p0 = par[2 * gid], p1 = par[2 * gid + 1];
      t0a[tid] = thax[p0]; s0a[tid] = sine[p0];
      t1a[tid] = thax[p1]; s1a[tid] = sine[p1];
      gida[tid] = gid;
    }
    __syncthreads();
    const float* Gm = &G[(size_t)(m * R_ + r) * 8448];
    {                                     // coop-build h (1 thread = row x 8 dims)
      int row = tid >> 4, seg = tid & 15, d0 = seg * 8;
      int t0 = t0a[row], t1 = t1a[row];
      float s0 = s0a[row], s1 = s1a[row];
      const float* pa = &Gm[t0 * 128 + d0];
      const float* pb = &Gm[(33 + t1) * 128 + d0];
      const float* pu = &Gm[4096 + d0];
      const float* pv = &Gm[8320 + d0];
      bf16x8 hv;
#pragma unroll
      for (int half = 0; half < 2; ++half) {
        float4 a = *(const float4*)(pa + half * 4);
        float4 b = *(const float4*)(pb + half * 4);
        float4 u = *(const float4*)(pu + half * 4);
        float4 v = *(const float4*)(pv + half * 4);
        hv[half * 4 + 0] = (__bf16)fmaxf(a.x + b.x + s0 * u.x + s1 * v.x, 0.f);
        hv[half * 4 + 1] = (__bf16)fmaxf(a.y + b.y + s0 * u.y + s1 * v.y, 0.f);
        hv[half * 4 + 2] = (__bf16)fmaxf(a.z + b.z + s0 * u.z + s1 * v.z, 0.f);
        hv[half * 4 + 3] = (__bf16)fmaxf(a.w + b.w + s0 * u.w + s1 * v.w, 0.f);
      }
      *(bf16x8*)&h_lds[row * 128 + (d0 ^ ((row & 7) << 3))] = hv;
    }
    __syncthreads();
    int l15 = lane & 15, l4 = lane >> 4;  // GEMM2: 4 waves x 2 f each
    const unsigned short* w2b = &W2T[(size_t)(m * R_ + r) * D_ * D_];
    f32x4 acc[2];
    acc[0] = (f32x4){0.f, 0.f, 0.f, 0.f};
    acc[1] = (f32x4){0.f, 0.f, 0.f, 0.f};
#pragma unroll
    for (int kc = 0; kc < 4; ++kc) {
      int d0 = kc * 32 + l4 * 8;
      bf16x8 a2 = ldb8(&h_lds[l15 * 128 + (d0 ^ ((l15 & 7) << 3))]);
#pragma unroll
      for (int f = 0; f < 2; ++f) {
        int fg = w * 2 + f;
        bf16x8 b = ldb8(&w2b[(fg * 16 + l15) * D_ + d0]);
        acc[f] = __builtin_amdgcn_mfma_f32_16x16x32_bf16(a2, b, acc[f], 0, 0, 0);
      }
    }
    float tw1 = tweaks[m * 2 + 1];
    const float* b2v = &b2[(m * R_ + r) * D_];
    __syncthreads();                      // done reading h_lds (GEMM2)
#pragma unroll
    for (int i = 0; i < 4; ++i) {
      int row = l4 * 4 + i;
      int g = base + row;
#pragma unroll
      for (int f = 0; f < 2; ++f) {
        int e = (w * 2 + f) * 16 + l15;
        unsigned short val = f2bu(acc[f][i] + b2v[e] + tw1);
        h_lds[row * 128 + (e ^ ((row & 7) << 3))] = val;
        if (g < cnt) sd[(size_t)(m * ND_ + gida[row]) * D_ + e] = val;
      }
    }
    __syncthreads();
    // fused eval: out @ We1 -> relu -> we2
    f32x4 ae[2];
    ae[0] = (f32x4){0.f, 0.f, 0.f, 0.f};
    ae[1] = (f32x4){0.f, 0.f, 0.f, 0.f};
    const unsigned short* we1b = &We1T[(size_t)m * D_ * D_];
#pragma unroll
    for (int kc = 0; kc < 4; ++kc) {
      int d0 = kc * 32 + l4 * 8;
      bf16x8 a2 = ldb8(&h_lds[l15 * 128 + (d0 ^ ((l15 & 7) << 3))]);
#pragma unroll
      for (int f = 0; f < 2; ++f) {
        int fg = w * 2 + f;
        bf16x8 b = ldb8(&we1b[(fg * 16 + l15) * D_ + d0]);
        ae[f] = __builtin_amdgcn_mfma_f32_16x16x32_bf16(a2, b, ae[f], 0, 0, 0);
      }
    }
    float part[4] = {0.f, 0.f, 0.f, 0.f};
#pragma unroll
    for (int f = 0; f < 2; ++f) {
      int e = (w * 2 + f) * 16 + l15;
      float bb = be1[m * D_ + e];
      float wv = we2[m * D_ + e];
#pragma unroll
      for (int i = 0; i < 4; ++i) {
        float he = ae[f][i] + bb;
        he = he > 0.f ? he : 0.f;
        part[i] += he * wv;
      }
    }
#pragma unroll
    for (int mask = 1; mask < 16; mask <<= 1) {
#pragma unroll
      for (int i = 0; i < 4; ++i) part[i] += __shfl_xor(part[i], mask, 64);
    }
    if (l15 == 0) {
#pragma unroll
      for (int i = 0; i < 4; ++i) red2[w * 16 + l4 * 4 + i] = part[i];
    }
    __syncthreads();
    if (tid < 16) {
      int g = base + tid;
      float v6[4] = {0.f, 0.f, 0.f, 0.f};
      if (g < cnt) {
        float logit = red2[tid] + red2[16 + tid] + red2[32 + tid] + red2[48 + tid]
                    + be2[m] + tweaks[m * 2 + 0];
        int grow = NI_ + gida[tid];
        float p_ = pos[grow], n_ = neg[grow];
        float lse = log1pf(__expf(-fabsf(logit)));
        v6[0] = p_ * (fmaxf(-logit, 0.f) + lse);
        v6[1] = n_ * (fmaxf(logit, 0.f) + lse);
        v6[2] = logit >= 0.f ? p_ : 0.f;
        v6[3] = logit < 0.f ? n_ : 0.f;
      }
#pragma unroll
      for (int mask = 1; mask < 16; mask <<= 1) {
#pragma unroll
        for (int qq = 0; qq < 4; ++qq) v6[qq] += __shfl_xor(v6[qq], mask, 64);
      }
      if (tid == 0) {
        int slot = 512 + r * 80 + tile;
        pA[m * PSTRIDE_ + slot] = v6[0];
        pB[m * PSTRIDE_ + slot] = v6[1];
        pPok[m * PSTRIDE_ + slot] = v6[2];
        pNok[m * PSTRIDE_ + slot] = v6[3];
      }
    }
  } else if (bid < 2304) {                // ---------- eval-init ----------
    int q = bid - 1280;
    int m = q >> 9, xb = q & 511;
    float* lea = sbuf;                    // [p=64][t=32][2]
    float* lwb = sbuf + 4096;             // [e=128][{EB,we2}]
    float* red = sbuf + 4352;
    for (int i = tid; i < 4096; i += 256) lea[i] = EA2[m * 4096 + i];
    if (tid < 256) lwb[tid] = EWB[m * 256 + tid];
    __syncthreads();
    int row = xb * 256 + tid;
    int t = thax[row];
    float s = sine[row];
    float acc = 0.f;
#pragma unroll 8
    for (int p = 0; p < 64; ++p) {
      float2 ea = *(const float2*)&lea[(p * 32 + t) * 2];
      float4 wb = *(const float4*)&lwb[p * 4];
      float x0 = fmaf(s, wb.x, ea.x); x0 = fmaxf(x0, 0.f);
      acc = fmaf(x0, wb.y, acc);
      float x1 = fmaf(s, wb.z, ea.y); x1 = fmaxf(x1, 0.f);
      acc = fmaf(x1, wb.w, acc);
    }
    float logit = acc + be2[m] + tweaks[m * 2 + 0];
    float p_ = pos[row], n_ = neg[row];
    float lse = log1pf(__expf(-fabsf(logit)));
    float v[6];
    v[0] = p_ * (fmaxf(-logit, 0.f) + lse);
    v[1] = n_ * (fmaxf(logit, 0.f) + lse);
    v[2] = logit >= 0.f ? p_ : 0.f;
    v[3] = logit < 0.f ? n_ : 0.f;
    v[4] = p_; v[5] = n_;
#pragma unroll
    for (int mask = 1; mask < 64; mask <<= 1) {
#pragma unroll
      for (int k = 0; k < 6; ++k) v[k] += __shfl_xor(v[k], mask, 64);
    }
    if (lane == 0) {
#pragma unroll
      for (int k = 0; k < 6; ++k) red[k * 16 + w] = v[k];
    }
    __syncthreads();
    if (tid == 0) {
      float t6[6];
#pragma unroll
      for (int k = 0; k < 6; ++k)
        t6[k] = red[k * 16 + 0] + red[k * 16 + 1] + red[k * 16 + 2] + red[k * 16 + 3];
      pA[m * PSTRIDE_ + xb] = t6[0];
      pB[m * PSTRIDE_ + xb] = t6[1];
      pPok[m * PSTRIDE_ + xb] = t6[2];
      pNok[m * PSTRIDE_ + xb] = t6[3];
      if (m == 0) { pTp[xb] = t6[4]; pTn[xb] = t6[5]; }
    }
  } else {                                // ---------- deriv pos/neg total ----------
    int j = bid - 2304;                   // 0: pos, 1: neg
    float* red = sbuf;
    const float* src = j ? neg : pos;
    float s = 0.f;
    for (int i = NI_ + tid; i < N_; i += 256) s += src[i];
#pragma unroll
    for (int mask = 1; mask < 64; mask <<= 1) s += __shfl_xor(s, mask, 64);
    if (lane == 0) red[w] = s;
    __syncthreads();
    if (tid == 0) {
      float t = red[0] + red[1] + red[2] + red[3];
      if (j == 0) pTp[1152] = t; else pTn[1152] = t;
    }
  }
}

// ================= slowA: all-layer slow rows with fast/init parents ===========
// grid (6, 8, 2), 128 threads (2 waves, f-split 4+4). Parents ready after main.
__global__ __launch_bounds__(128) void slowA_kernel(
    const int* thax, const float* sine, const int* par,
    const float* b1, const float* b2, const float* tweaks,
    const float* pos, const float* neg,
    const float* be1, const float* we2, const float* be2,
    const unsigned short* tab, const unsigned short* svec,
    const unsigned short* W1T, const unsigned short* W2T,
    const unsigned short* We1T,
    const int* cfgA, const int* slowAlist,
    unsigned short* sd,
    float* pA, float* pB, float* pPok, float* pNok) {
  int tile = blockIdx.x, r = blockIdx.y, m = blockIdx.z;
  int cnt = cfgA[r];
  int base = tile * 16;
  if (base >= cnt) return;
  int tid = threadIdx.x;
  int w = tid >> 6, lane = tid & 63;
  int l15 = lane & 15, l4 = lane >> 4;
  __shared__ unsigned short h_lds[16 * 128];
  __shared__ float red2[32];
  __shared__ int grows[16];

  if (tid < 16) {
    int loc = base + tid; if (loc >= cnt) loc = cnt - 1;
    grows[tid] = slowAlist[r * ACAP_ + loc];
  }
  __syncthreads();
  int g0 = grows[l15];
  int p0 = par[2 * g0], p1 = par[2 * g0 + 1];
  const unsigned short* w1b = &W1T[(size_t)(m * R_ + r) * D_ * 256];
  const unsigned short* w2b = &W2T[(size_t)(m * R_ + r) * D_ * D_];
  const unsigned short* we1b = &We1T[(size_t)m * D_ * D_];

  bf16x8 av[8];
#pragma unroll
  for (int kc = 0; kc < 8; ++kc) {
    int k = kc * 32 + l4 * 8;
    int p = (k < 128) ? p0 : p1;
    av[kc] = node_chunk(m, p, k & 127, tab, svec, sd, thax, sine);
  }
  f32x4 acch[4];
#pragma unroll
  for (int f = 0; f < 4; ++f) acch[f] = (f32x4){0.f, 0.f, 0.f, 0.f};
#pragma unroll
  for (int kc = 0; kc < 8; ++kc) {
    int k = kc * 32 + l4 * 8;
#pragma unroll
    for (int f = 0; f < 4; ++f) {
      int fg = w * 4 + f;
      bf16x8 b = ldb8(&w1b[(fg * 16 + l15) * 256 + k]);
      acch[f] = __builtin_amdgcn_mfma_f32_16x16x32_bf16(av[kc], b, acch[f], 0, 0, 0);
    }
  }
  const float* b1v = &b1[(m * R_ + r) * D_];
#pragma unroll
  for (int f = 0; f < 4; ++f) {
    int d = (w * 4 + f) * 16 + l15;
    float bb = b1v[d];
#pragma unroll
    for (int i = 0; i < 4; ++i) {
      int row = l4 * 4 + i;
      float h = acch[f][i] + bb;
      h = h > 0.f ? h : 0.f;
      h_lds[row * 128 + (d ^ ((row & 7) << 3))] = f2bu(h);
    }
  }
  __syncthreads();
  f32x4 acco[4];
#pragma unroll
  for (int f = 0; f < 4; ++f) acco[f] = (f32x4){0.f, 0.f, 0.f, 0.f};
#pragma unroll
  for (int kc = 0; kc < 4; ++kc) {
    int d0 = kc * 32 + l4 * 8;
    bf16x8 a2 = ldb8(&h_lds[l15 * 128 + (d0 ^ ((l15 & 7) << 3))]);
#pragma unroll
    for (int f = 0; f < 4; ++f) {
      int fg = w * 4 + f;
      bf16x8 b = ldb8(&w2b[(fg * 16 + l15) * D_ + d0]);
      acco[f] = __builtin_amdgcn_mfma_f32_16x16x32_bf16(a2, b, acco[f], 0, 0, 0);
    }
  }
  float tw1 = tweaks[m * 2 + 1];
  const float* b2v = &b2[(m * R_ + r) * D_];
  __syncthreads();
#pragma unroll
  for (int i = 0; i < 4; ++i) {
    int row = l4 * 4 + i;
    int g = base + row;
#pragma unroll
    for (int f = 0; f < 4; ++f) {
      int e = (w * 4 + f) * 16 + l15;
      unsigned short val = f2bu(acco[f][i] + b2v[e] + tw1);
      h_lds[row * 128 + (e ^ ((row & 7) << 3))] = val;
      if (g < cnt) sd[(size_t)(m * ND_ + grows[row]) * D_ + e] = val;
    }
  }
  __syncthreads();
  f32x4 ae[4];
#pragma unroll
  for (int f = 0; f < 4; ++f) ae[f] = (f32x4){0.f, 0.f, 0.f, 0.f};
#pragma unroll
  for (int kc = 0; kc < 4; ++kc) {
    int d0 = kc * 32 + l4 * 8;
    bf16x8 a2 = ldb8(&h_lds[l15 * 128 + (d0 ^ ((l15 & 7) << 3))]);
#pragma unroll
    for (int f = 0; f < 4; ++f) {
      int fg = w * 4 + f;
      bf16x8 b = ldb8(&we1b[(fg * 16 + l15) * D_ + d0]);
      ae[f] = __builtin_amdgcn_mfma_f32_16x16x32_bf16(a2, b, ae[f], 0, 0, 0);
    }
  }
  float part[4] = {0.f, 0.f, 0.f, 0.f};
#pragma unroll
  for (int f = 0; f < 4; ++f) {
    int e = (w * 4 + f) * 16 + l15;
    float bb = be1[m * D_ + e];
    float wv = we2[m * D_ + e];
#pragma unroll
    for (int i = 0; i < 4; ++i) {
      float he = ae[f][i] + bb;
      he = he > 0.f ? he : 0.f;
      part[i] += he * wv;
    }
  }
#pragma unroll
  for (int mask = 1; mask < 16; mask <<= 1) {
#pragma unroll
    for (int i = 0; i < 4; ++i) part[i] += __shfl_xor(part[i], mask, 64);
  }
  if (l15 == 0) {
#pragma unroll
    for (int i = 0; i < 4; ++i) red2[w * 16 + l4 * 4 + i] = part[i];
  }
  __syncthreads();
  if (tid < 16) {
    int g = base + tid;
    float v6[4] = {0.f, 0.f, 0.f, 0.f};
    if (g < cnt) {
      float logit = red2[tid] + red2[16 + tid] + be2[m] + tweaks[m * 2 + 0];
      int grow = NI_ + grows[tid];
      float p_ = pos[grow], n_ = neg[grow];
      float lse = log1pf(__expf(-fabsf(logit)));
      v6[0] = p_ * (fmaxf(-logit, 0.f) + lse);
      v6[1] = n_ * (fmaxf(logit, 0.f) + lse);
      v6[2] = logit >= 0.f ? p_ : 0.f;
      v6[3] = logit < 0.f ? n_ : 0.f;
    }
#pragma unroll
    for (int mask = 1; mask < 16; mask <<= 1) {
#pragma unroll
      for (int qq = 0; qq < 4; ++qq) v6[qq] += __shfl_xor(v6[qq], mask, 64);
    }
    if (tid == 0) {
      int slot = 1153 + r * 6 + tile;
      pA[m * PSTRIDE_ + slot] = v6[0];
      pB[m * PSTRIDE_ + slot] = v6[1];
      pPok[m * PSTRIDE_ + slot] = v6[2];
      pNok[m * PSTRIDE_ + slot] = v6[3];
    }
  }
}

// ================= slowB layer l: chained slow rows (+fused eval), spin-free ====
// grid (2, 8, 2), 128 threads. Parents ready after slowA / previous slowB launch.
__global__ __launch_bounds__(128) void slowB_kernel(int l,
    const int* thax, const float* sine, const int* par,
    const float* b1, const float* b2, const float* tweaks,
    const float* pos, const float* neg,
    const float* be1, const float* we2, const float* be2,
    const unsigned short* tab, const unsigned short* svec,
    const unsigned short* W1T, const unsigned short* W2T,
    const unsigned short* We1T,
    const int* cB24, const int* slowBlist,
    unsigned short* sd,
    float* pA, float* pB, float* pPok, float* pNok) {
  int tile = blockIdx.x, r = blockIdx.y, m = blockIdx.z;
  int bkt = (l - 1) * 8 + r;
  int cnt = cB24[bkt];
  int base = tile * 16;
  if (base >= cnt) return;
  int tid = threadIdx.x;
  int w = tid >> 6, lane = tid & 63;
  int l15 = lane & 15, l4 = lane >> 4;
  __shared__ unsigned short h_lds[16 * 128];
  __shared__ float red2[32];
  __shared__ int grows[16];

  if (tid < 16) {
    int loc = base + tid; if (loc >= cnt) loc = cnt - 1;
    grows[tid] = slowBlist[bkt * BCAP_ + loc];
  }
  __syncthreads();
  int g0 = grows[l15];
  int p0 = par[2 * g0], p1 = par[2 * g0 + 1];
  const unsigned short* w1b = &W1T[(size_t)(m * R_ + r) * D_ * 256];
  const unsigned short* w2b = &W2T[(size_t)(m * R_ + r) * D_ * D_];
  const unsigned short* we1b = &We1T[(size_t)m * D_ * D_];

  bf16x8 av[8];
#pragma unroll
  for (int kc = 0; kc < 8; ++kc) {
    int k = kc * 32 + l4 * 8;
    int p = (k < 128) ? p0 : p1;
    av[kc] = node_chunk(m, p, k & 127, tab, svec, sd, thax, sine);
  }
  f32x4 acch[4];
#pragma unroll
  for (int f = 0; f < 4; ++f) acch[f] = (f32x4){0.f, 0.f, 0.f, 0.f};
#pragma unroll
  for (int kc = 0; kc < 8; ++kc) {
    int k = kc * 32 + l4 * 8;
#pragma unroll
    for (int f = 0; f < 4; ++f) {
      int fg = w * 4 + f;
      bf16x8 b = ldb8(&w1b[(fg * 16 + l15) * 256 + k]);
      acch[f] = __builtin_amdgcn_mfma_f32_16x16x32_bf16(av[kc], b, acch[f], 0, 0, 0);
    }
  }
  const float* b1v = &b1[(m * R_ + r) * D_];
#pragma unroll
  for (int f = 0; f < 4; ++f) {
    int d = (w * 4 + f) * 16 + l15;
    float bb = b1v[d];
#pragma unroll
    for (int i = 0; i < 4; ++i) {
      int row = l4 * 4 + i;
      float h = acch[f][i] + bb;
      h = h > 0.f ? h : 0.f;
      h_lds[row * 128 + (d ^ ((row & 7) << 3))] = f2bu(h);
    }
  }
  __syncthreads();
  f32x4 acco[4];
#pragma unroll
  for (int f = 0; f < 4; ++f) acco[f] = (f32x4){0.f, 0.f, 0.f, 0.f};
#pragma unroll
  for (int kc = 0; kc < 4; ++kc) {
    int d0 = kc * 32 + l4 * 8;
    bf16x8 a2 = ldb8(&h_lds[l15 * 128 + (d0 ^ ((l15 & 7) << 3))]);
#pragma unroll
    for (int f = 0; f < 4; ++f) {
      int fg = w * 4 + f;
      bf16x8 b = ldb8(&w2b[(fg * 16 + l15) * D_ + d0]);
      acco[f] = __builtin_amdgcn_mfma_f32_16x16x32_bf16(a2, b, acco[f], 0, 0, 0);
    }
  }
  float tw1 = tweaks[m * 2 + 1];
  const float* b2v = &b2[(m * R_ + r) * D_];
  __syncthreads();
#pragma unroll
  for (int i = 0; i < 4; ++i) {
    int row = l4 * 4 + i;
    int g = base + row;
#pragma unroll
    for (int f = 0; f < 4; ++f) {
      int e = (w * 4 + f) * 16 + l15;
      unsigned short val = f2bu(acco[f][i] + b2v[e] + tw1);
      h_lds[row * 128 + (e ^ ((row & 7) << 3))] = val;
      if (g < cnt) sd[(size_t)(m * ND_ + grows[row]) * D_ + e] = val;
    }
  }
  __syncthreads();
  f32x4 ae[4];
#pragma unroll
  for (int f = 0; f < 4; ++f) ae[f] = (f32x4){0.f, 0.f, 0.f, 0.f};
#pragma unroll
  for (int kc = 0; kc < 4; ++kc) {
    int d0 = kc * 32 + l4 * 8;
    bf16x8 a2 = ldb8(&h_lds[l15 * 128 + (d0 ^ ((l15 & 7) << 3))]);
#pragma unroll
    for (int f = 0; f < 4; ++f) {
      int fg = w * 4 + f;
      bf16x8 b = ldb8(&we1b[(fg * 16 + l15) * D_ + d0]);
      ae[f] = __builtin_amdgcn_mfma_f32_16x16x32_bf16(a2, b, ae[f], 0, 0, 0);
    }
  }
  float part[4] = {0.f, 0.f, 0.f, 0.f};
#pragma unroll
  for (int f = 0; f < 4; ++f) {
    int e = (w * 4 + f) * 16 + l15;
    float bb = be1[m * D_ + e];
    float wv = we2[m * D_ + e];
#pragma unroll
    for (int i = 0; i < 4; ++i) {
      float he = ae[f][i] + bb;
      he = he > 0.f ? he : 0.f;
      part[i] += he * wv;
    }
  }
#pragma unroll
  for (int mask = 1; mask < 16; mask <<= 1) {
#pragma unroll
    for (int i = 0; i < 4; ++i) part[i] += __shfl_xor(part[i], mask, 64);
  }
  if (l15 == 0) {
#pragma unroll
    for (int i = 0; i < 4; ++i) red2[w * 16 + l4 * 4 + i] = part[i];
  }
  __syncthreads();
  if (tid < 16) {
    int g = base + tid;
    float v6[4] = {0.f, 0.f, 0.f, 0.f};
    if (g < cnt) {
      float logit = red2[tid] + red2[16 + tid] + be2[m] + tweaks[m * 2 + 0];
      int grow = NI_ + grows[tid];
      float p_ = pos[grow], n_ = neg[grow];
      float lse = log1pf(__expf(-fabsf(logit)));
      v6[0] = p_ * (fmaxf(-logit, 0.f) + lse);
      v6[1] = n_ * (fmaxf(logit, 0.f) + lse);
      v6[2] = logit >= 0.f ? p_ : 0.f;
      v6[3] = logit < 0.f ? n_ : 0.f;
    }
#pragma unroll
    for (int mask = 1; mask < 16; mask <<= 1) {
#pragma unroll
      for (int qq = 0; qq < 4; ++qq) v6[qq] += __shfl_xor(v6[qq], mask, 64);
    }
    if (tid == 0) {
      int slot = 1201 + (l - 2) * 16 + r * 2 + tile;
      pA[m * PSTRIDE_ + slot] = v6[0];
      pB[m * PSTRIDE_ + slot] = v6[1];
      pPok[m * PSTRIDE_ + slot] = v6[2];
      pNok[m * PSTRIDE_ + slot] = v6[3];
    }
  }
}

// ---------------- deterministic final reduction ----------------
__global__ __launch_bounds__(256) void finalize_kernel(
    const float* pA, const float* pB, const float* pPok, const float* pNok,
    const float* pTp, const float* pTn, float* out) {
  __shared__ float lred[10][4];
  const float* srcs[10] = {pA, pA + PSTRIDE_, pB, pB + PSTRIDE_,
                           pPok, pPok + PSTRIDE_, pNok, pNok + PSTRIDE_,
                           pTp, pTn};
  int tid = threadIdx.x;
  int w = tid >> 6, lane = tid & 63;
#pragma unroll
  for (int q = 0; q < 10; ++q) {
    float s = 0.f;
    for (int i = tid; i < PUSED_; i += 256) s += srcs[q][i];
#pragma unroll
    for (int mask = 1; mask < 64; mask <<= 1) s += __shfl_xor(s, mask, 64);
    if (lane == 0) lred[q][w] = s;
  }
  __syncthreads();
  if (tid == 0) {
    float totals[10];
#pragma unroll
    for (int q = 0; q < 10; ++q)
      totals[q] = lred[q][0] + lred[q][1] + lred[q][2] + lred[q][3];
    float tp = totals[8], tn = totals[9];
    float pw = tn / tp;
    out[0] = pw * totals[0] + totals[2];
    out[1] = pw * totals[1] + totals[3];
    out[2] = totals[4]; out[3] = totals[5];
    out[4] = totals[6]; out[5] = totals[7];
    out[6] = tp; out[7] = tn;
  }
}

extern "C" void kernel_launch(void* const* d_in, const int* in_sizes, int n_in,
                              void* d_out, int out_size, void* d_ws, size_t ws_size,
                              hipStream_t stream) {
  const int*   thax = (const int*)d_in[0];
  const float* sine = (const float*)d_in[1];
  const int*   par  = (const int*)d_in[2];
  const int*   ridx = (const int*)d_in[3];
  const float* pos  = (const float*)d_in[4];
  const float* neg  = (const float*)d_in[5];
  const float* init_table = (const float*)d_in[6];
  const float* s_vec = (const float*)d_in[7];
  const float* W1 = (const float*)d_in[8];
  const float* b1 = (const float*)d_in[9];
  const float* W2 = (const float*)d_in[10];
  const float* b2 = (const float*)d_in[11];
  const float* tweaks = (const float*)d_in[12];
  const float* We1 = (const float*)d_in[13];
  const float* be1 = (const float*)d_in[14];
  const float* we2 = (const float*)d_in[15];
  const float* be2 = (const float*)d_in[16];

  char* ws = (char*)d_ws;
  unsigned short* W1T  = (unsigned short*)(ws + OFF_W1T);
  unsigned short* W2T  = (unsigned short*)(ws + OFF_W2T);
  unsigned short* We1T = (unsigned short*)(ws + OFF_WE1T);
  unsigned short* tab  = (unsigned short*)(ws + OFF_TAB);
  unsigned short* svec = (unsigned short*)(ws + OFF_SVEC);
  float* EA2  = (float*)(ws + OFF_EA2);
  float* EWB  = (float*)(ws + OFF_EWB);
  float* pA   = (float*)(ws + OFF_PA);
  float* pB   = (float*)(ws + OFF_PB);
  float* pPok = (float*)(ws + OFF_PPOK);
  float* pNok = (float*)(ws + OFF_PNOK);
  float* pTp  = (float*)(ws + OFF_PTP);
  float* pTn  = (float*)(ws + OFF_PTN);
  float* G    = (float*)(ws + OFF_G);
  unsigned short* sd = (unsigned short*)(ws + OFF_STORE);
  int* fastlist  = (int*)(ws + OFF_FLIST);
  int* slowAlist = (int*)(ws + OFF_SAL);
  int* slowBlist = (int*)(ws + OFF_SBL);
  int* cfg       = (int*)(ws + OFF_CFG);
  int* cfgA      = (int*)(ws + OFF_CFGA);
  int* cB24      = (int*)(ws + OFF_CB24);

  megaprep_kernel<<<1404, 256, 0, stream>>>(
      W1, W2, We1, init_table, s_vec, b1, be1, we2, ridx, par,
      W1T, W2T, We1T, tab, svec, G, EA2, EWB,
      fastlist, slowAlist, slowBlist, cfg, cfgA, cB24,
      (unsigned int*)pA);
  main_kernel<<<2306, 256, 0, stream>>>(
      thax, sine, par, pos, neg, b2, tweaks, G, W2T, We1T, EA2, EWB,
      be1, we2, be2, cfg, fastlist, sd,
      pA, pB, pPok, pNok, pTp, pTn);
  slowA_kernel<<<dim3(6, R_, M_), 128, 0, stream>>>(
      thax, sine, par, b1, b2, tweaks, pos, neg, be1, we2, be2,
      tab, svec, W1T, W2T, We1T, cfgA, slowAlist, sd,
      pA, pB, pPok, pNok);
  for (int l = 2; l < L_; ++l) {          // layer-1 slow rows are all in slowA
    slowB_kernel<<<dim3(2, R_, M_), 128, 0, stream>>>(
        l, thax, sine, par, b1, b2, tweaks, pos, neg, be1, we2, be2,
        tab, svec, W1T, W2T, We1T, cB24, slowBlist, sd,
        pA, pB, pPok, pNok);
  }
  finalize_kernel<<<1, 256, 0, stream>>>(pA, pB, pPok, pNok, pTp, pTn,
                                         (float*)d_out);
}

// Round 18
// 92.430 us; speedup vs baseline: 3.9446x; 1.0361x over previous
//
#include <hip/hip_runtime.h>
#include <hip/hip_bf16.h>

#define M_ 2
#define D_ 128
#define NI_ 131072
#define L_ 4
#define NPL_ 2048
#define R_ 8
#define T_ 32
#define N_ (NI_ + L_ * NPL_)   // 139264
#define ND_ (L_ * NPL_)        // 8192 deriv nodes
#define PSTRIDE_ 1792          // per-model partial stride (floats)
#define PUSED_ 1665            // 512 init + 640 fast + 1 posneg + 512 slow
#define FCAP_ 1280             // fast rows capacity per rule (exp ~979)
#define SCAP_ 512              // slow rows capacity total    (exp ~368)
#define CCAP_ 24               // ancestor-closure cap per slow row (max possible 15)

typedef __bf16 bf16x8 __attribute__((ext_vector_type(8)));
typedef float f32x4 __attribute__((ext_vector_type(4)));
typedef unsigned short u16x4 __attribute__((ext_vector_type(4)));

// ---- ws layout (bytes) ----
#define OFF_W2T    0u            // [M][R][128(e)][128(d)] bf16 = 524288
#define OFF_WE1T   524288u       // [M][128(e)][128(d)] bf16    = 65536
#define OFF_TAB    589824u       // [M][T][128] bf16            = 16384
#define OFF_SVEC   606208u       // [M][128] bf16               = 512
#define OFF_EA2    606720u       // [M][64][32][2] f32          = 32768
#define OFF_EWB    639488u       // [M][128][2] f32             = 2048
#define OFF_PA     641536u       // [2][1792] f32 (pA..pTn contiguous 71680 B)
#define OFF_PB     655872u
#define OFF_PPOK   670208u
#define OFF_PNOK   684544u
#define OFF_PTP    698880u       // [1792] f32
#define OFF_PTN    706048u       // end 713216
#define OFF_G      713216u       // [M][R][2][33][128] f32 = 540672 (b1 folded slot-a t<32)
#define OFF_FLIST  1253888u      // [8][1280] int = 40960
#define OFF_SLIST  1294848u      // [512] int = 2048
#define OFF_CFG    1296896u      // [12] int (0..7 fast counts, 8 slow count)

__device__ __forceinline__ unsigned short f2bu(float f) {
  unsigned int u = __float_as_uint(f);
  u += 0x7fffu + ((u >> 16) & 1u);        // RNE (finite values only)
  return (unsigned short)(u >> 16);
}
__device__ __forceinline__ float bfu2f(unsigned short u) {
  return __uint_as_float((unsigned int)u << 16);
}
__device__ __forceinline__ bf16x8 ldb8(const unsigned short* p) {
  return *reinterpret_cast<const bf16x8*>(p);
}

// ================= mega-prep =================
// jobs: [0,8) classify fast rule r; 8 classify slow; 9 zero partials;
//       10 tab/svec; [11,45) eaprep; [45,573) gprep; [573,861) transposes (W2,We1).
__global__ __launch_bounds__(256) void megaprep_kernel(
    const float* W1, const float* W2, const float* We1,
    const float* init_table, const float* s_vec,
    const float* b1, const float* be1, const float* we2,
    const int* ridx, const int* par,
    unsigned short* W2T, unsigned short* We1T,
    unsigned short* tab, unsigned short* svec,
    float* G, float* EA2, float* EWB,
    int* fastlist, int* slowlist, int* cfg, unsigned int* pzero) {
  __shared__ float smem[1056];
  __shared__ int lcnt;
  int job = blockIdx.x;
  int tid = threadIdx.x;

  if (job < 9) {                         // -------- classify (ballot-compaction) ----
    int* out; int cap;
    if (job < 8) { out = fastlist + job * FCAP_; cap = FCAP_; }
    else         { out = slowlist;               cap = SCAP_; }
    if (tid == 0) lcnt = 0;
    __syncthreads();
    int lane = tid & 63;
    unsigned long long lmask_lt = (1ull << lane) - 1ull;
    for (int g = tid; g < ND_; g += 256) {
      int p0 = par[2 * g], p1 = par[2 * g + 1];
      bool fast = (p0 < NI_) && (p1 < NI_);
      bool match = (job < 8) ? (fast && ridx[g] == job) : (!fast);
      unsigned long long mask = __ballot(match);
      if (mask) {
        int leader = __ffsll((unsigned long long)mask) - 1;
        int pre = __popcll(mask & lmask_lt);
        int base_ = 0;
        if (lane == leader) base_ = atomicAdd(&lcnt, __popcll(mask));
        base_ = __shfl(base_, leader, 64);
        if (match) {
          int idx = base_ + pre;
          if (idx < cap) out[idx] = g;
        }
      }
    }
    __syncthreads();
    if (tid == 0) {
      int c = lcnt; if (c > cap) c = cap;
      cfg[job] = c;
    }
  } else if (job == 9) {                 // -------- zero partials (71680 B) --------
    for (int i = tid; i < 17920; i += 256) pzero[i] = 0u;
  } else if (job == 10) {                // -------- tab/svec convert --------
    for (int i = tid; i < 8448; i += 256) {
      if (i < 8192) tab[i] = f2bu(init_table[i]);
      else svec[i - 8192] = f2bu(s_vec[i - 8192]);
    }
  } else if (job < 45) {                 // -------- eaprep: eval-init tables --------
    int q = job - 11;
    int m = q / 17, t = (q % 17) * 2 + (tid >> 7);
    int e = tid & 127;
    if (t <= 32) {
      const float* vec = (t < 32) ? &init_table[(size_t)(m * T_ + t) * D_]
                                  : &s_vec[(size_t)m * D_];
      const float* w = &We1[(size_t)m * D_ * D_];
      float acc = 0.f;
#pragma unroll 8
      for (int d = 0; d < 128; ++d) acc = fmaf(vec[d], w[d * D_ + e], acc);
      if (t < 32) {
        EA2[m * 4096 + ((e >> 1) * 32 + t) * 2 + (e & 1)] = acc + be1[m * D_ + e];
      } else {
        EWB[(m * D_ + e) * 2 + 0] = acc;
        EWB[(m * D_ + e) * 2 + 1] = we2[m * D_ + e];
      }
    }
  } else if (job < 573) {                // -------- gprep: G[m][r][slot][t][e] --------
    int q = job - 45;
    int t = q / 16, mr = q & 15;         // t in [0,32], 32 == svec row
    int m = mr >> 3;
    int slot = tid >> 7, e = tid & 127;
    const float* vec = (t < 32) ? &init_table[(size_t)(m * T_ + t) * D_]
                                : &s_vec[(size_t)m * D_];
    if (tid < 128) smem[tid] = vec[tid];
    __syncthreads();
    const float* w = &W1[((size_t)mr * 256 + slot * 128) * D_];
    float acc = 0.f;
#pragma unroll 8
    for (int c = 0; c < 128; ++c) acc = fmaf(smem[c], w[c * D_ + e], acc);
    if (slot == 0 && t < 32) acc += b1[mr * D_ + e];   // fold b1 into slot-a rows
    G[((size_t)(mr * 2 + slot) * 33 + t) * D_ + e] = acc;
  } else {                               // -------- transposes (W2: 256, We1: 32) ----
    int q0 = job - 573;
    const float* src; unsigned short* dst;
    int rblk, cblk;
    if (q0 < 256) {
      int z = q0 >> 4;
      src = W2 + (size_t)z * 16384; dst = W2T + (size_t)z * 16384;
      rblk = (q0 & 15) >> 2; cblk = q0 & 3;
    } else {
      int q = q0 - 256; int z = q >> 4;
      src = We1 + (size_t)z * 16384; dst = We1T + (size_t)z * 16384;
      rblk = (q & 15) >> 2; cblk = q & 3;
    }
    int r0 = rblk * 32, c0 = cblk * 32;
    float (*tile)[33] = (float(*)[33])smem;
    int tx = tid & 31, ty = tid >> 5;
#pragma unroll
    for (int k = 0; k < 4; ++k)
      tile[ty + 8 * k][tx] = src[(size_t)(r0 + ty + 8 * k) * D_ + c0 + tx];
    __syncthreads();
#pragma unroll
    for (int k = 0; k < 4; ++k)
      dst[(size_t)(c0 + ty + 8 * k) * D_ + r0 + tx] = f2bu(tile[tx][ty + 8 * k]);
  }
}

// ================= main: fast rows + eval-init + posneg + slow closure rows =====
// grid 3330. bid<1280: fast tile. bid<2304: eval-init. bid<2306: posneg.
// bid>=2306: slow row (m=q>>9, si=q&511) — analytic ancestor recompute, no deps.
__global__ __launch_bounds__(256) void main_kernel(
    const int* thax, const float* sine, const int* par, const int* ridx,
    const float* pos, const float* neg,
    const float* W1, const float* b1, const float* b2, const float* tweaks,
    const float* G, const unsigned short* W2T, const unsigned short* We1T,
    const unsigned short* tab, const unsigned short* svec,
    const float* EA2, const float* EWB,
    const float* be1, const float* we2, const float* be2,
    const int* cfg, const int* fastlist, const int* slowlist,
    float* pA, float* pB, float* pPok, float* pNok, float* pTp, float* pTn) {
  __shared__ float sbuf[4448];
  int bid = blockIdx.x;
  int tid = threadIdx.x;
  int w = tid >> 6, lane = tid & 63;

  if (bid < 1280) {                       // ---------- fast rows ----------
    int m = bid / 640, q = bid % 640;
    int r = q / 80, tile = q % 80;
    int cnt = cfg[r];
    int base = tile * 16;
    if (base >= cnt) return;
    unsigned short* h_lds = (unsigned short*)sbuf;       // [16][128] bf16
    int*   t0a  = (int*)(sbuf + 1024);
    int*   t1a  = t0a + 16;
    float* s0a  = (float*)(t1a + 16);
    float* s1a  = s0a + 16;
    int*   gida = (int*)(s1a + 16);
    float* red2 = sbuf + 1104;                           // [4][16]
    if (tid < 16) {
      int loc = base + tid; if (loc >= cnt) loc = cnt - 1;
      int gid = fastlist[r * FCAP_ + loc];
      int p0 = par[2 * gid], p1 = par[2 * gid + 1];
      t0a[tid] = thax[p0]; s0a[tid] = sine[p0];
      t1a[tid] = thax[p1]; s1a[tid] = sine[p1];
      gida[tid] = gid;
    }
    __syncthreads();
    const float* Gm = &G[(size_t)(m * R_ + r) * 8448];
    {                                     // coop-build h (1 thread = row x 8 dims)
      int row = tid >> 4, seg = tid & 15, d0 = seg * 8;
      int t0 = t0a[row], t1 = t1a[row];
      float s0 = s0a[row], s1 = s1a[row];
      const float* pa = &Gm[t0 * 128 + d0];
      const float* pb = &Gm[(33 + t1) * 128 + d0];
      const float* pu = &Gm[4096 + d0];
      const float* pv = &Gm[8320 + d0];
      bf16x8 hv;
#pragma unroll
      for (int half = 0; half < 2; ++half) {
        float4 a = *(const float4*)(pa + half * 4);
        float4 b = *(const float4*)(pb + half * 4);
        float4 u = *(const float4*)(pu + half * 4);
        float4 v = *(const float4*)(pv + half * 4);
        hv[half * 4 + 0] = (__bf16)fmaxf(a.x + b.x + s0 * u.x + s1 * v.x, 0.f);
        hv[half * 4 + 1] = (__bf16)fmaxf(a.y + b.y + s0 * u.y + s1 * v.y, 0.f);
        hv[half * 4 + 2] = (__bf16)fmaxf(a.z + b.z + s0 * u.z + s1 * v.z, 0.f);
        hv[half * 4 + 3] = (__bf16)fmaxf(a.w + b.w + s0 * u.w + s1 * v.w, 0.f);
      }
      *(bf16x8*)&h_lds[row * 128 + (d0 ^ ((row & 7) << 3))] = hv;
    }
    __syncthreads();
    int l15 = lane & 15, l4 = lane >> 4;  // GEMM2: 4 waves x 2 f each
    const unsigned short* w2b = &W2T[(size_t)(m * R_ + r) * D_ * D_];
    f32x4 acc[2];
    acc[0] = (f32x4){0.f, 0.f, 0.f, 0.f};
    acc[1] = (f32x4){0.f, 0.f, 0.f, 0.f};
#pragma unroll
    for (int kc = 0; kc < 4; ++kc) {
      int d0 = kc * 32 + l4 * 8;
      bf16x8 a2 = ldb8(&h_lds[l15 * 128 + (d0 ^ ((l15 & 7) << 3))]);
#pragma unroll
      for (int f = 0; f < 2; ++f) {
        int fg = w * 2 + f;
        bf16x8 b = ldb8(&w2b[(fg * 16 + l15) * D_ + d0]);
        acc[f] = __builtin_amdgcn_mfma_f32_16x16x32_bf16(a2, b, acc[f], 0, 0, 0);
      }
    }
    float tw1 = tweaks[m * 2 + 1];
    const float* b2v = &b2[(m * R_ + r) * D_];
    __syncthreads();                      // done reading h_lds (GEMM2)
#pragma unroll
    for (int i = 0; i < 4; ++i) {
      int row = l4 * 4 + i;
#pragma unroll
      for (int f = 0; f < 2; ++f) {
        int e = (w * 2 + f) * 16 + l15;
        h_lds[row * 128 + (e ^ ((row & 7) << 3))] = f2bu(acc[f][i] + b2v[e] + tw1);
      }
    }
    __syncthreads();
    // fused eval: out @ We1 -> relu -> we2
    f32x4 ae[2];
    ae[0] = (f32x4){0.f, 0.f, 0.f, 0.f};
    ae[1] = (f32x4){0.f, 0.f, 0.f, 0.f};
    const unsigned short* we1b = &We1T[(size_t)m * D_ * D_];
#pragma unroll
    for (int kc = 0; kc < 4; ++kc) {
      int d0 = kc * 32 + l4 * 8;
      bf16x8 a2 = ldb8(&h_lds[l15 * 128 + (d0 ^ ((l15 & 7) << 3))]);
#pragma unroll
      for (int f = 0; f < 2; ++f) {
        int fg = w * 2 + f;
        bf16x8 b = ldb8(&we1b[(fg * 16 + l15) * D_ + d0]);
        ae[f] = __builtin_amdgcn_mfma_f32_16x16x32_bf16(a2, b, ae[f], 0, 0, 0);
      }
    }
    float part[4] = {0.f, 0.f, 0.f, 0.f};
#pragma unroll
    for (int f = 0; f < 2; ++f) {
      int e = (w * 2 + f) * 16 + l15;
      float bb = be1[m * D_ + e];
      float wv = we2[m * D_ + e];
#pragma unroll
      for (int i = 0; i < 4; ++i) {
        float he = ae[f][i] + bb;
        he = he > 0.f ? he : 0.f;
        part[i] += he * wv;
      }
    }
#pragma unroll
    for (int mask = 1; mask < 16; mask <<= 1) {
#pragma unroll
      for (int i = 0; i < 4; ++i) part[i] += __shfl_xor(part[i], mask, 64);
    }
    if (l15 == 0) {
#pragma unroll
      for (int i = 0; i < 4; ++i) red2[w * 16 + l4 * 4 + i] = part[i];
    }
    __syncthreads();
    if (tid < 16) {
      int g = base + tid;
      float v6[4] = {0.f, 0.f, 0.f, 0.f};
      if (g < cnt) {
        float logit = red2[tid] + red2[16 + tid] + red2[32 + tid] + red2[48 + tid]
                    + be2[m] + tweaks[m * 2 + 0];
        int grow = NI_ + gida[tid];
        float p_ = pos[grow], n_ = neg[grow];
        float lse = log1pf(__expf(-fabsf(logit)));
        v6[0] = p_ * (fmaxf(-logit, 0.f) + lse);
        v6[1] = n_ * (fmaxf(logit, 0.f) + lse);
        v6[2] = logit >= 0.f ? p_ : 0.f;
        v6[3] = logit < 0.f ? n_ : 0.f;
      }
#pragma unroll
      for (int mask = 1; mask < 16; mask <<= 1) {
#pragma unroll
        for (int qq = 0; qq < 4; ++qq) v6[qq] += __shfl_xor(v6[qq], mask, 64);
      }
      if (tid == 0) {
        int slot = 512 + r * 80 + tile;
        pA[m * PSTRIDE_ + slot] = v6[0];
        pB[m * PSTRIDE_ + slot] = v6[1];
        pPok[m * PSTRIDE_ + slot] = v6[2];
        pNok[m * PSTRIDE_ + slot] = v6[3];
      }
    }
  } else if (bid < 2304) {                // ---------- eval-init ----------
    int q = bid - 1280;
    int m = q >> 9, xb = q & 511;
    float* lea = sbuf;                    // [p=64][t=32][2]
    float* lwb = sbuf + 4096;             // [e=128][{EB,we2}]
    float* red = sbuf + 4352;
    for (int i = tid; i < 4096; i += 256) lea[i] = EA2[m * 4096 + i];
    if (tid < 256) lwb[tid] = EWB[m * 256 + tid];
    __syncthreads();
    int row = xb * 256 + tid;
    int t = thax[row];
    float s = sine[row];
    float acc = 0.f;
#pragma unroll 8
    for (int p = 0; p < 64; ++p) {
      float2 ea = *(const float2*)&lea[(p * 32 + t) * 2];
      float4 wb = *(const float4*)&lwb[p * 4];
      float x0 = fmaf(s, wb.x, ea.x); x0 = fmaxf(x0, 0.f);
      acc = fmaf(x0, wb.y, acc);
      float x1 = fmaf(s, wb.z, ea.y); x1 = fmaxf(x1, 0.f);
      acc = fmaf(x1, wb.w, acc);
    }
    float logit = acc + be2[m] + tweaks[m * 2 + 0];
    float p_ = pos[row], n_ = neg[row];
    float lse = log1pf(__expf(-fabsf(logit)));
    float v[6];
    v[0] = p_ * (fmaxf(-logit, 0.f) + lse);
    v[1] = n_ * (fmaxf(logit, 0.f) + lse);
    v[2] = logit >= 0.f ? p_ : 0.f;
    v[3] = logit < 0.f ? n_ : 0.f;
    v[4] = p_; v[5] = n_;
#pragma unroll
    for (int mask = 1; mask < 64; mask <<= 1) {
#pragma unroll
      for (int k = 0; k < 6; ++k) v[k] += __shfl_xor(v[k], mask, 64);
    }
    if (lane == 0) {
#pragma unroll
      for (int k = 0; k < 6; ++k) red[k * 16 + w] = v[k];
    }
    __syncthreads();
    if (tid == 0) {
      float t6[6];
#pragma unroll
      for (int k = 0; k < 6; ++k)
        t6[k] = red[k * 16 + 0] + red[k * 16 + 1] + red[k * 16 + 2] + red[k * 16 + 3];
      pA[m * PSTRIDE_ + xb] = t6[0];
      pB[m * PSTRIDE_ + xb] = t6[1];
      pPok[m * PSTRIDE_ + xb] = t6[2];
      pNok[m * PSTRIDE_ + xb] = t6[3];
      if (m == 0) { pTp[xb] = t6[4]; pTn[xb] = t6[5]; }
    }
  } else if (bid < 2306) {                // ---------- deriv pos/neg total ----------
    int j = bid - 2304;                   // 0: pos, 1: neg
    float* red = sbuf;
    const float* src = j ? neg : pos;
    float s = 0.f;
    for (int i = NI_ + tid; i < N_; i += 256) s += src[i];
#pragma unroll
    for (int mask = 1; mask < 64; mask <<= 1) s += __shfl_xor(s, mask, 64);
    if (lane == 0) red[w] = s;
    __syncthreads();
    if (tid == 0) {
      float t = red[0] + red[1] + red[2] + red[3];
      if (j == 0) pTp[1152] = t; else pTn[1152] = t;
    }
  } else {                                // ---------- slow row: analytic closure ----
    int q = bid - 2306;
    int m = q >> 9, si = q & 511;
    if (si >= cfg[8]) return;
    int*   list  = (int*)sbuf;                              // [CCAP_]
    int*   meta  = (int*)(sbuf + 24);                       // nn, slot0, slot1
    unsigned short* catl = (unsigned short*)(sbuf + 32);    // [256] bf16
    float* hbuf  = sbuf + 160;                              // [128]
    float* hp0   = sbuf + 288;                              // [128]
    float* hp1   = sbuf + 416;                              // [128]
    unsigned short* cache = (unsigned short*)(sbuf + 544);  // [CCAP_][128] bf16

    int g_row = slowlist[si];
    if (tid == 0) {
      int nn = 0;
      list[nn++] = g_row;
      for (int i = 0; i < nn; ++i) {              // BFS closure over deriv ancestors
        int g = list[i];
        for (int s = 0; s < 2; ++s) {
          int p = par[2 * g + s];
          if (p >= NI_) {
            int pg = p - NI_;
            bool found = false;
            for (int jj = 0; jj < nn; ++jj) if (list[jj] == pg) { found = true; break; }
            if (!found && nn < CCAP_) list[nn++] = pg;
          }
        }
      }
      for (int i = 1; i < nn; ++i) {              // sort ascending (parents first)
        int v = list[i]; int jj = i - 1;
        while (jj >= 0 && list[jj] > v) { list[jj + 1] = list[jj]; --jj; }
        list[jj + 1] = v;
      }
      meta[0] = nn;
    }
    __syncthreads();
    int NN = meta[0];
    float tw1 = tweaks[m * 2 + 1];
    for (int j = 0; j < NN; ++j) {
      int g = list[j];
      int r = ridx[g];
      int p0 = par[2 * g], p1 = par[2 * g + 1];
      bool fastn = (p0 < NI_) && (p1 < NI_);
      if (fastn) {                                // h via G tables
        if (tid < 128) {
          int d = tid;
          const float* Gm = &G[(size_t)(m * R_ + r) * 8448];
          float hv = Gm[thax[p0] * 128 + d] + Gm[(33 + thax[p1]) * 128 + d]
                   + sine[p0] * Gm[4096 + d] + sine[p1] * Gm[8320 + d];
          hbuf[d] = bfu2f(f2bu(fmaxf(hv, 0.f)));
        }
        __syncthreads();
      } else {                                    // slow node: GEMM1 over cat
        if (tid == 0) {
          int s0 = -1, s1 = -1;
          if (p0 >= NI_) for (int jj = 0; jj < j; ++jj) if (list[jj] == p0 - NI_) { s0 = jj; break; }
          if (p1 >= NI_) for (int jj = 0; jj < j; ++jj) if (list[jj] == p1 - NI_) { s1 = jj; break; }
          meta[1] = s0; meta[2] = s1;
        }
        __syncthreads();
        {
          int c = tid; int p = (c < 128) ? p0 : p1; int cc = c & 127;
          int slot = (c < 128) ? meta[1] : meta[2];
          unsigned short v;
          if (p < NI_) {
            float tv = bfu2f(tab[(m * T_ + thax[p]) * D_ + cc])
                     + sine[p] * bfu2f(svec[m * D_ + cc]);
            v = f2bu(tv);
          } else {
            v = cache[slot * 128 + cc];
          }
          catl[c] = v;
        }
        __syncthreads();
        int d = tid & 127, half = tid >> 7;
        const float* w1r = &W1[(((size_t)(m * R_ + r)) * 256 + half * 128) * D_];
        float acc = 0.f;
#pragma unroll 8
        for (int c = 0; c < 128; ++c)
          acc = fmaf(bfu2f(catl[half * 128 + c]), w1r[(size_t)c * D_ + d], acc);
        if (half == 0) hp0[d] = acc; else hp1[d] = acc;
        __syncthreads();
        if (tid < 128) {
          float hv = b1[(m * R_ + r) * D_ + tid] + hp0[tid] + hp1[tid];
          hbuf[tid] = bfu2f(f2bu(fmaxf(hv, 0.f)));
        }
        __syncthreads();
      }
      // GEMM2 -> cache[j]
      {
        int e = tid & 127, half = tid >> 7;
        const u16x4* w2r4 = (const u16x4*)&W2T[((size_t)(m * R_ + r) * D_ + e) * D_ + half * 64];
        float acc = 0.f;
#pragma unroll
        for (int dd = 0; dd < 16; ++dd) {
          u16x4 wv = w2r4[dd];
          int db = half * 64 + dd * 4;
          acc = fmaf(bfu2f(wv[0]), hbuf[db + 0], acc);
          acc = fmaf(bfu2f(wv[1]), hbuf[db + 1], acc);
          acc = fmaf(bfu2f(wv[2]), hbuf[db + 2], acc);
          acc = fmaf(bfu2f(wv[3]), hbuf[db + 3], acc);
        }
        if (half == 0) hp0[e] = acc; else hp1[e] = acc;
      }
      __syncthreads();
      if (tid < 128) {
        float o = hp0[tid] + hp1[tid] + b2[(m * R_ + r) * D_ + tid] + tw1;
        cache[j * 128 + tid] = f2bu(o);
      }
      __syncthreads();
    }
    // fused eval of the row (largest index -> last after sort)
    int jr = NN - 1;
    {
      int e = tid & 127, half = tid >> 7;
      const u16x4* wer4 = (const u16x4*)&We1T[((size_t)m * D_ + e) * D_ + half * 64];
      float acc = 0.f;
#pragma unroll
      for (int dd = 0; dd < 16; ++dd) {
        u16x4 wv = wer4[dd];
        int db = half * 64 + dd * 4;
        acc = fmaf(bfu2f(wv[0]), bfu2f(cache[jr * 128 + db + 0]), acc);
        acc = fmaf(bfu2f(wv[1]), bfu2f(cache[jr * 128 + db + 1]), acc);
        acc = fmaf(bfu2f(wv[2]), bfu2f(cache[jr * 128 + db + 2]), acc);
        acc = fmaf(bfu2f(wv[3]), bfu2f(cache[jr * 128 + db + 3]), acc);
      }
      if (half == 0) hp0[e] = acc; else hp1[e] = acc;
    }
    __syncthreads();
    if (tid < 128) {
      float he = hp0[tid] + hp1[tid] + be1[m * D_ + tid];
      he = he > 0.f ? he : 0.f;
      hbuf[tid] = he * we2[m * D_ + tid];
    }
    __syncthreads();
    if (tid < 64) {
      float s = hbuf[tid] + hbuf[tid + 64];
#pragma unroll
      for (int mask = 1; mask < 64; mask <<= 1) s += __shfl_xor(s, mask, 64);
      if (tid == 0) {
        float logit = s + be2[m] + tweaks[m * 2 + 0];
        int grow = NI_ + g_row;
        float p_ = pos[grow], n_ = neg[grow];
        float lse = log1pf(__expf(-fabsf(logit)));
        int slot = 1153 + si;
        pA[m * PSTRIDE_ + slot] = p_ * (fmaxf(-logit, 0.f) + lse);
        pB[m * PSTRIDE_ + slot] = n_ * (fmaxf(logit, 0.f) + lse);
        pPok[m * PSTRIDE_ + slot] = logit >= 0.f ? p_ : 0.f;
        pNok[m * PSTRIDE_ + slot] = logit < 0.f ? n_ : 0.f;
      }
    }
  }
}

// ---------------- deterministic final reduction ----------------
__global__ __launch_bounds__(256) void finalize_kernel(
    const float* pA, const float* pB, const float* pPok, const float* pNok,
    const float* pTp, const float* pTn, float* out) {
  __shared__ float lred[10][4];
  const float* srcs[10] = {pA, pA + PSTRIDE_, pB, pB + PSTRIDE_,
                           pPok, pPok + PSTRIDE_, pNok, pNok + PSTRIDE_,
                           pTp, pTn};
  int tid = threadIdx.x;
  int w = tid >> 6, lane = tid & 63;
#pragma unroll
  for (int q = 0; q < 10; ++q) {
    float s = 0.f;
    for (int i = tid; i < PUSED_; i += 256) s += srcs[q][i];
#pragma unroll
    for (int mask = 1; mask < 64; mask <<= 1) s += __shfl_xor(s, mask, 64);
    if (lane == 0) lred[q][w] = s;
  }
  __syncthreads();
  if (tid == 0) {
    float totals[10];
#pragma unroll
    for (int q = 0; q < 10; ++q)
      totals[q] = lred[q][0] + lred[q][1] + lred[q][2] + lred[q][3];
    float tp = totals[8], tn = totals[9];
    float pw = tn / tp;
    out[0] = pw * totals[0] + totals[2];
    out[1] = pw * totals[1] + totals[3];
    out[2] = totals[4]; out[3] = totals[5];
    out[4] = totals[6]; out[5] = totals[7];
    out[6] = tp; out[7] = tn;
  }
}

extern "C" void kernel_launch(void* const* d_in, const int* in_sizes, int n_in,
                              void* d_out, int out_size, void* d_ws, size_t ws_size,
                              hipStream_t stream) {
  const int*   thax = (const int*)d_in[0];
  const float* sine = (const float*)d_in[1];
  const int*   par  = (const int*)d_in[2];
  const int*   ridx = (const int*)d_in[3];
  const float* pos  = (const float*)d_in[4];
  const float* neg  = (const float*)d_in[5];
  const float* init_table = (const float*)d_in[6];
  const float* s_vec = (const float*)d_in[7];
  const float* W1 = (const float*)d_in[8];
  const float* b1 = (const float*)d_in[9];
  const float* W2 = (const float*)d_in[10];
  const float* b2 = (const float*)d_in[11];
  const float* tweaks = (const float*)d_in[12];
  const float* We1 = (const float*)d_in[13];
  const float* be1 = (const float*)d_in[14];
  const float* we2 = (const float*)d_in[15];
  const float* be2 = (const float*)d_in[16];

  char* ws = (char*)d_ws;
  unsigned short* W2T  = (unsigned short*)(ws + OFF_W2T);
  unsigned short* We1T = (unsigned short*)(ws + OFF_WE1T);
  unsigned short* tab  = (unsigned short*)(ws + OFF_TAB);
  unsigned short* svec = (unsigned short*)(ws + OFF_SVEC);
  float* EA2  = (float*)(ws + OFF_EA2);
  float* EWB  = (float*)(ws + OFF_EWB);
  float* pA   = (float*)(ws + OFF_PA);
  float* pB   = (float*)(ws + OFF_PB);
  float* pPok = (float*)(ws + OFF_PPOK);
  float* pNok = (float*)(ws + OFF_PNOK);
  float* pTp  = (float*)(ws + OFF_PTP);
  float* pTn  = (float*)(ws + OFF_PTN);
  float* G    = (float*)(ws + OFF_G);
  int* fastlist = (int*)(ws + OFF_FLIST);
  int* slowlist = (int*)(ws + OFF_SLIST);
  int* cfg      = (int*)(ws + OFF_CFG);

  megaprep_kernel<<<861, 256, 0, stream>>>(
      W1, W2, We1, init_table, s_vec, b1, be1, we2, ridx, par,
      W2T, We1T, tab, svec, G, EA2, EWB,
      fastlist, slowlist, cfg, (unsigned int*)pA);
  main_kernel<<<3330, 256, 0, stream>>>(
      thax, sine, par, ridx, pos, neg, W1, b1, b2, tweaks,
      G, W2T, We1T, tab, svec, EA2, EWB, be1, we2, be2,
      cfg, fastlist, slowlist,
      pA, pB, pPok, pNok, pTp, pTn);
  finalize_kernel<<<1, 256, 0, stream>>>(pA, pB, pPok, pNok, pTp, pTn,
                                         (float*)d_out);
}